// Round 6
// baseline (282.125 us; speedup 1.0000x reference)
//
#include <hip/hip_runtime.h>
#include <hip/hip_bf16.h>

// Problem constants (fixed by reference)
#define Bn 16
#define Tn 64
#define Nn 256
#define Kn 8
#define dn 8
#define Dn 64
#define TDn 128   // 2*D

typedef __bf16 bf16x8 __attribute__((ext_vector_type(8)));
typedef __bf16 bf16x4 __attribute__((ext_vector_type(4)));
typedef __bf16 bf16x2 __attribute__((ext_vector_type(2)));
typedef float  f32x4  __attribute__((ext_vector_type(4)));
typedef float  f32x16 __attribute__((ext_vector_type(16)));

#if __has_builtin(__builtin_amdgcn_exp2f)
#define EXP2F(x) __builtin_amdgcn_exp2f(x)
#else
#define EXP2F(x) exp2f(x)
#endif

#if __has_builtin(__builtin_amdgcn_rcpf)
#define RCPF(x) __builtin_amdgcn_rcpf(x)
#else
#define RCPF(x) (1.0f / (x))
#endif

// tanh-form GELU via native exp2 + rcp (~10 VALU ops vs ~60 for libm erff).
__device__ __forceinline__ float geluf(float x) {
    const float x2 = x * x;
    const float v = x * fmaf(0.10294342f, x2, 2.30220920f);   // 2*log2e*0.79788456*(x+0.044715x^3)
    const float w = EXP2F(-fabsf(v));
    const float r = RCPF(1.0f + w);
    const float t = (1.0f - w) * r;                            // tanh(|u|)
    return fmaf(0.5f * fabsf(x), t, 0.5f * x);
}

__device__ __forceinline__ bf16x8 bzero8() {
    bf16x8 z;
    #pragma unroll
    for (int e = 0; e < 8; ++e) z[e] = (__bf16)0.0f;
    return z;
}

__device__ __forceinline__ bf16x8 pack8(float4 f0, float4 f1) {
    bf16x8 a;
    a[0] = (__bf16)f0.x; a[1] = (__bf16)f0.y;
    a[2] = (__bf16)f0.z; a[3] = (__bf16)f0.w;
    a[4] = (__bf16)f1.x; a[5] = (__bf16)f1.y;
    a[6] = (__bf16)f1.z; a[7] = (__bf16)f1.w;
    return a;
}

// ---- Kernel 1: convert all weights fp32 -> bf16 into d_ws ----
// ws layout (bf16): [0,24576) Wqkv rows 0-63=W12,64-127=W13,128-191=W14 (row=128 k)
//                   [24576,28672) W15 [64][64]; [28672,32768) W16 [64][64]
__global__ void convert_weights(const float* __restrict__ W12, const float* __restrict__ W13,
                                const float* __restrict__ W14, const float* __restrict__ W15,
                                const float* __restrict__ W16, __bf16* __restrict__ ws)
{
    const int i = blockIdx.x * 256 + threadIdx.x;   // 0..32767
    float v;
    if      (i < 8192)  v = W12[i];
    else if (i < 16384) v = W13[i - 8192];
    else if (i < 24576) v = W14[i - 16384];
    else if (i < 28672) v = W15[i - 24576];
    else                v = W16[i - 28672];
    ws[i] = (__bf16)v;
}

// ---- Kernel 2: fused block per (b,n); 256 threads = 4 waves ----
// LDS 27,648 B -> 5 blocks/CU (20 waves).
// Regions: [0,9216)      vt[64][72] bf16 (V transposed, row = h*8+d)
//          [9216,18432)  qs[64][72]  (q in phase 2-3, attention output after phase 3)
//          [18432,27648) ks[64][72]  (k in phase 2-3, MLP hidden in phase 4)
// Phases 2/4a/4b use SWAPPED MFMA operands (D = W.H^T) so epilogues are b64/dwordx4 stores.
// Phase 3 uses 32x32x16 MFMAs with P fully in registers (lane^32 swap repack).
// R6: explicit software-pipelined prefetch of all weight/bias global loads (the R5
// counters showed 56% empty issue slots = exposed vmem latency; VGPR was only 48 of
// the ~96 budget at 5 waves/EU, so registers are spent on load depth instead).
__global__ __launch_bounds__(256, 5)
void tam_fused(const float* __restrict__ X,
               const float* __restrict__ STE,
               const float* __restrict__ b12, const float* __restrict__ b13,
               const float* __restrict__ b14, const float* __restrict__ b15,
               const float* __restrict__ b16,
               const __bf16* __restrict__ Wb,   // converted weights in ws
               float* __restrict__ Out)
{
    __shared__ __align__(16) char smem[27648];
    __bf16 (*vt)[72] = reinterpret_cast<__bf16 (*)[72]>(smem);           // [64][72]: V^T
    __bf16 (*qs)[72] = reinterpret_cast<__bf16 (*)[72]>(smem + 9216);    // [64][72]
    __bf16 (*ks)[72] = reinterpret_cast<__bf16 (*)[72]>(smem + 18432);   // [64][72]

    const int bn   = blockIdx.x;
    const int b    = bn >> 8;     // / Nn
    const int n    = bn & 255;    // % Nn
    const int tid  = threadIdx.x;
    const int lane = tid & 63;
    const int wv   = __builtin_amdgcn_readfirstlane(tid >> 6);
    const int cl   = lane & 15;          // 16x16 MFMA col-in-tile / A-row-in-tile
    const int quad = lane >> 4;
    const int kb   = quad * 8;           // 16x16 MFMA k-offset
    const int m0   = wv * 16;            // this wave's row-tile

    const __bf16* Wqkv = Wb;             // [192][128]
    const __bf16* W15b = Wb + 24576;     // [64][64]
    const __bf16* W16b = Wb + 28672;     // [64][64]

    // ---------------- Phase 2: qkv = gelu(H @ Wqkv^T + b), depth-2 prefetch pipeline ---------
    // q/k swapped operands (D[feat][t]); v unswapped (D[t][feat]) feeding transposed vt.
    // q written pre-scaled by 1/sqrt(8)*log2(e) (attention uses exp2 directly).
    {
        // Issue all 8 H (X/STE) loads first.
        const int t = m0 + cl;
        const size_t rb = (((size_t)b * Tn + t) * Nn + n) * (size_t)Dn;
        const float4* Xr = reinterpret_cast<const float4*>(X + rb);
        const float4* Sr = reinterpret_cast<const float4*>(STE + rb);
        const float4 hx0 = Xr[quad * 2],     hx1 = Xr[quad * 2 + 1];
        const float4 hx2 = Xr[8 + quad * 2], hx3 = Xr[8 + quad * 2 + 1];
        const float4 hs0 = Sr[quad * 2],     hs1 = Sr[quad * 2 + 1];
        const float4 hs2 = Sr[8 + quad * 2], hs3 = Sr[8 + quad * 2 + 1];

        // Prefetch weight tiles 0,1 (+biases) while H loads are in flight.
        bf16x8 wq[2][4];
        float4 bq[2];
        float  vb[2] = {0.f, 0.f};
        #pragma unroll
        for (int kk = 0; kk < 4; ++kk)
            wq[0][kk] = *reinterpret_cast<const bf16x8*>(&Wqkv[(0 + cl) * TDn + kk * 32 + kb]);
        bq[0] = *reinterpret_cast<const float4*>(&b12[0 + 4 * quad]);
        #pragma unroll
        for (int kk = 0; kk < 4; ++kk)
            wq[1][kk] = *reinterpret_cast<const bf16x8*>(&Wqkv[(16 + cl) * TDn + kk * 32 + kb]);
        bq[1] = *reinterpret_cast<const float4*>(&b12[16 + 4 * quad]);

        // Pack A-frags (VALU overlaps the in-flight loads above).
        bf16x8 af[4];
        af[0] = pack8(hx0, hx1);
        af[1] = pack8(hx2, hx3);
        af[2] = pack8(hs0, hs1);
        af[3] = pack8(hs2, hs3);

        #pragma unroll
        for (int nt = 0; nt < 12; ++nt) {
            const int c  = nt & 1;        // compile-time after full unroll
            const int n0 = nt * 16;
            f32x4 acc = {0.f, 0.f, 0.f, 0.f};
            if (nt < 8) {
                // swapped: D = W.H^T -> row = feat n0+4q+r, col = t m0+cl
                #pragma unroll
                for (int kk = 0; kk < 4; ++kk)
                    acc = __builtin_amdgcn_mfma_f32_16x16x32_bf16(wq[c][kk], af[kk], acc, 0, 0, 0);
            } else {
                // unswapped: D = H.W^T -> row = t m0+4q+r, col = feat n0-128+cl
                #pragma unroll
                for (int kk = 0; kk < 4; ++kk)
                    acc = __builtin_amdgcn_mfma_f32_16x16x32_bf16(af[kk], wq[c][kk], acc, 0, 0, 0);
            }
            const float4 bs    = bq[c];   // consumed before prefetch overwrites
            const float  vbias = vb[c];

            // Prefetch tile nt+2 into the slot just freed (flies under epilogue + next MFMAs).
            if (nt < 10) {
                const int nn = nt + 2;
                #pragma unroll
                for (int kk = 0; kk < 4; ++kk)
                    wq[c][kk] = *reinterpret_cast<const bf16x8*>(
                        &Wqkv[(nn * 16 + cl) * TDn + kk * 32 + kb]);
                if      (nn < 4) bq[c] = *reinterpret_cast<const float4*>(&b12[nn * 16 + 4 * quad]);
                else if (nn < 8) bq[c] = *reinterpret_cast<const float4*>(&b13[(nn - 4) * 16 + 4 * quad]);
                else             vb[c] = b14[(nn - 8) * 16 + cl];
            }

            if (nt < 4) {
                bf16x4 pk;
                pk[0] = (__bf16)(geluf(acc[0] + bs.x) * 0.51006951f);
                pk[1] = (__bf16)(geluf(acc[1] + bs.y) * 0.51006951f);
                pk[2] = (__bf16)(geluf(acc[2] + bs.z) * 0.51006951f);
                pk[3] = (__bf16)(geluf(acc[3] + bs.w) * 0.51006951f);
                *reinterpret_cast<bf16x4*>(&qs[m0 + cl][n0 + 4 * quad]) = pk;
            } else if (nt < 8) {
                bf16x4 pk;
                pk[0] = (__bf16)geluf(acc[0] + bs.x);
                pk[1] = (__bf16)geluf(acc[1] + bs.y);
                pk[2] = (__bf16)geluf(acc[2] + bs.z);
                pk[3] = (__bf16)geluf(acc[3] + bs.w);
                *reinterpret_cast<bf16x4*>(&ks[m0 + cl][n0 - 64 + 4 * quad]) = pk;
            } else {
                bf16x4 pv;
                #pragma unroll
                for (int r = 0; r < 4; ++r) pv[r] = (__bf16)geluf(acc[r] + vbias);
                // col = h*8+d; rows m0+4q..+3 are consecutive t -> contiguous in vt[col][t]
                *reinterpret_cast<bf16x4*>(&vt[n0 - 128 + cl][m0 + 4 * quad]) = pv;
            }
        }
    }
    __syncthreads();

    // ---------------- Phase 3: 32x32x16 MFMA attention, P fully in registers ----------
    // Wave wv owns heads {2wv, 2wv+1} = qs/ks/vt columns [16wv,16wv+16): column-disjoint
    // across waves -> no internal barriers. Per head, causal 64x64 needs 3 of 4 32x32 tiles.
    //   A: row = lane&31, k = (lane>>5)*8 + e;  B: col = lane&31, k = (lane>>5)*8 + e
    //   C: col = lane&31, row = (reg&3) + 8*(reg>>2) + 4*(lane>>5)
    {
        const int half = lane >> 5;
        const int l31  = lane & 31;

        for (int hh = 0; hh < 2; ++hh) {
            const int hc = 8 * (2 * wv + hh);

            // K A-frags (k = d 0..7 in half 0; half 1 zero-pads K=16 to d=8)
            bf16x8 kA0 = bzero8(), kA1 = bzero8(), qB0 = bzero8(), qB1 = bzero8();
            if (half == 0) {
                kA0 = *reinterpret_cast<const bf16x8*>(&ks[ 0 + l31][hc]);
                kA1 = *reinterpret_cast<const bf16x8*>(&ks[32 + l31][hc]);
                qB0 = *reinterpret_cast<const bf16x8*>(&qs[ 0 + l31][hc]);
                qB1 = *reinterpret_cast<const bf16x8*>(&qs[32 + l31][hc]);
            }
            // V^T A-frags per 16-tk chunk: row = d = l31 (<8 real), k = tk 16c+8*half..+7
            bf16x8 vA0 = bzero8(), vA1 = bzero8(), vA2 = bzero8(), vA3 = bzero8();
            if (l31 < 8) {
                vA0 = *reinterpret_cast<const bf16x8*>(&vt[hc + l31][ 0 + 8 * half]);
                vA1 = *reinterpret_cast<const bf16x8*>(&vt[hc + l31][16 + 8 * half]);
                vA2 = *reinterpret_cast<const bf16x8*>(&vt[hc + l31][32 + 8 * half]);
                vA3 = *reinterpret_cast<const bf16x8*>(&vt[hc + l31][48 + 8 * half]);
            }

            f32x16 zc16;
            #pragma unroll
            for (int r = 0; r < 16; ++r) zc16[r] = 0.f;

            // ================= tq-tile 0 (tq = l31; tk-tile 0 only, causal) =================
            {
                f32x16 S = __builtin_amdgcn_mfma_f32_32x32x16_bf16(kA0, qB0, zc16, 0, 0, 0);
                #pragma unroll
                for (int r = 0; r < 16; ++r) {
                    const int tk = (r & 3) + 8 * (r >> 2) + 4 * half;
                    S[r] = (tk > l31) ? -3.0e38f : S[r];
                }
                float mx = S[0];
                #pragma unroll
                for (int r = 1; r < 16; ++r) mx = fmaxf(mx, S[r]);
                mx = fmaxf(mx, __shfl_xor(mx, 32));
                float sum = 0.f;
                #pragma unroll
                for (int r = 0; r < 16; ++r) { const float p = EXP2F(S[r] - mx); S[r] = p; sum += p; }
                sum += __shfl_xor(sum, 32);

                unsigned u[8];
                #pragma unroll
                for (int i = 0; i < 8; ++i) {
                    union { __bf16 h[2]; unsigned w; } cv;
                    cv.h[0] = (__bf16)S[2 * i]; cv.h[1] = (__bf16)S[2 * i + 1];
                    u[i] = cv.w;
                }
                f32x16 O = zc16;
                #pragma unroll
                for (int c = 0; c < 2; ++c) {
                    const unsigned x0 = __shfl_xor(u[4 * c + 0], 32);
                    const unsigned x1 = __shfl_xor(u[4 * c + 1], 32);
                    const unsigned x2 = __shfl_xor(u[4 * c + 2], 32);
                    const unsigned x3 = __shfl_xor(u[4 * c + 3], 32);
                    union { unsigned w[4]; bf16x8 v; } bw;
                    bw.w[0] = half ? x2 : u[4 * c + 0];
                    bw.w[1] = half ? x3 : u[4 * c + 1];
                    bw.w[2] = half ? u[4 * c + 2] : x0;
                    bw.w[3] = half ? u[4 * c + 3] : x1;
                    O = __builtin_amdgcn_mfma_f32_32x32x16_bf16(c ? vA1 : vA0, bw.v, O, 0, 0, 0);
                }
                const float inv = RCPF(sum);
                bf16x4 ov;
                #pragma unroll
                for (int r = 0; r < 4; ++r) ov[r] = (__bf16)(O[r] * inv);
                *reinterpret_cast<bf16x4*>(&qs[l31][hc + 4 * half]) = ov;
            }

            // ================= tq-tile 1 (tq = 32+l31; tk-tiles 0 and 1) =================
            {
                f32x16 Sa = __builtin_amdgcn_mfma_f32_32x32x16_bf16(kA0, qB1, zc16, 0, 0, 0);
                f32x16 Sb = __builtin_amdgcn_mfma_f32_32x32x16_bf16(kA1, qB1, zc16, 0, 0, 0);
                #pragma unroll
                for (int r = 0; r < 16; ++r) {   // mask only the diagonal tile (tk 32..63)
                    const int tk = (r & 3) + 8 * (r >> 2) + 4 * half;
                    Sb[r] = (tk > l31) ? -3.0e38f : Sb[r];
                }
                float mx = Sa[0];
                #pragma unroll
                for (int r = 1; r < 16; ++r) mx = fmaxf(mx, Sa[r]);
                #pragma unroll
                for (int r = 0; r < 16; ++r) mx = fmaxf(mx, Sb[r]);
                mx = fmaxf(mx, __shfl_xor(mx, 32));
                float sum = 0.f;
                #pragma unroll
                for (int r = 0; r < 16; ++r) { const float p = EXP2F(Sa[r] - mx); Sa[r] = p; sum += p; }
                #pragma unroll
                for (int r = 0; r < 16; ++r) { const float p = EXP2F(Sb[r] - mx); Sb[r] = p; sum += p; }
                sum += __shfl_xor(sum, 32);

                unsigned ua[8], ub[8];
                #pragma unroll
                for (int i = 0; i < 8; ++i) {
                    union { __bf16 h[2]; unsigned w; } cv;
                    cv.h[0] = (__bf16)Sa[2 * i]; cv.h[1] = (__bf16)Sa[2 * i + 1];
                    ua[i] = cv.w;
                }
                #pragma unroll
                for (int i = 0; i < 8; ++i) {
                    union { __bf16 h[2]; unsigned w; } cv;
                    cv.h[0] = (__bf16)Sb[2 * i]; cv.h[1] = (__bf16)Sb[2 * i + 1];
                    ub[i] = cv.w;
                }
                f32x16 O = zc16;
                #pragma unroll
                for (int c = 0; c < 4; ++c) {
                    const unsigned* uu = (c < 2) ? ua : ub;
                    const int c2 = c & 1;
                    const unsigned x0 = __shfl_xor(uu[4 * c2 + 0], 32);
                    const unsigned x1 = __shfl_xor(uu[4 * c2 + 1], 32);
                    const unsigned x2 = __shfl_xor(uu[4 * c2 + 2], 32);
                    const unsigned x3 = __shfl_xor(uu[4 * c2 + 3], 32);
                    union { unsigned w[4]; bf16x8 v; } bw;
                    bw.w[0] = half ? x2 : uu[4 * c2 + 0];
                    bw.w[1] = half ? x3 : uu[4 * c2 + 1];
                    bw.w[2] = half ? uu[4 * c2 + 2] : x0;
                    bw.w[3] = half ? uu[4 * c2 + 3] : x1;
                    const bf16x8 vA = (c == 0) ? vA0 : (c == 1) ? vA1 : (c == 2) ? vA2 : vA3;
                    O = __builtin_amdgcn_mfma_f32_32x32x16_bf16(vA, bw.v, O, 0, 0, 0);
                }
                const float inv = RCPF(sum);
                bf16x4 ov;
                #pragma unroll
                for (int r = 0; r < 4; ++r) ov[r] = (__bf16)(O[r] * inv);
                *reinterpret_cast<bf16x4*>(&qs[32 + l31][hc + 4 * half]) = ov;
            }
        }
    }
    __syncthreads();

    // ---------------- Phase 4: MLP, all weight/bias loads front-issued ----------------
    {
        // Issue ALL W15 frags + b15 immediately (independent of LDS state).
        bf16x8 w15a[4], w15b[4];
        float4 b15v[4];
        #pragma unroll
        for (int nt = 0; nt < 4; ++nt) {
            const int n0 = nt * 16;
            w15a[nt] = *reinterpret_cast<const bf16x8*>(&W15b[(n0 + cl) * Dn + kb]);
            w15b[nt] = *reinterpret_cast<const bf16x8*>(&W15b[(n0 + cl) * Dn + 32 + kb]);
            b15v[nt] = *reinterpret_cast<const float4*>(&b15[n0 + 4 * quad]);
        }
        const bf16x8 h0 = *reinterpret_cast<const bf16x8*>(&qs[m0 + cl][kb]);
        const bf16x8 h1 = *reinterpret_cast<const bf16x8*>(&qs[m0 + cl][32 + kb]);

        // 4a MFMAs first (swapped: D[feat][t]), held in acc4.
        f32x4 acc4[4];
        #pragma unroll
        for (int nt = 0; nt < 4; ++nt) {
            f32x4 acc = {0.f, 0.f, 0.f, 0.f};
            acc = __builtin_amdgcn_mfma_f32_16x16x32_bf16(w15a[nt], h0, acc, 0, 0, 0);
            acc = __builtin_amdgcn_mfma_f32_16x16x32_bf16(w15b[nt], h1, acc, 0, 0, 0);
            acc4[nt] = acc;
        }

        // Issue W16 + b16 loads BEFORE the 4a epilogue: they fly under the gelu VALU.
        bf16x8 w16a[4], w16b[4];
        float4 b16v[4];
        #pragma unroll
        for (int nt = 0; nt < 4; ++nt) {
            const int n0 = nt * 16;
            w16a[nt] = *reinterpret_cast<const bf16x8*>(&W16b[(n0 + cl) * Dn + kb]);
            w16b[nt] = *reinterpret_cast<const bf16x8*>(&W16b[(n0 + cl) * Dn + 32 + kb]);
            b16v[nt] = *reinterpret_cast<const float4*>(&b16[n0 + 4 * quad]);
        }

        // 4a epilogue: hidden = gelu(acc + b15) -> ks (b64 stores, swapped layout).
        #pragma unroll
        for (int nt = 0; nt < 4; ++nt) {
            const int n0 = nt * 16;
            const float4 bs = b15v[nt];
            bf16x4 pk;
            pk[0] = (__bf16)geluf(acc4[nt][0] + bs.x);
            pk[1] = (__bf16)geluf(acc4[nt][1] + bs.y);
            pk[2] = (__bf16)geluf(acc4[nt][2] + bs.z);
            pk[3] = (__bf16)geluf(acc4[nt][3] + bs.w);
            *reinterpret_cast<bf16x4*>(&ks[m0 + cl][n0 + 4 * quad]) = pk;
        }
        // No barrier: 4b reads only this wave's 16 rows of ks (same-wave DS in-order).

        const bf16x8 g0 = *reinterpret_cast<const bf16x8*>(&ks[m0 + cl][kb]);
        const bf16x8 g1 = *reinterpret_cast<const bf16x8*>(&ks[m0 + cl][32 + kb]);
        const size_t ob = (((size_t)(b * Tn + m0 + cl)) * Nn + n) * (size_t)Dn;
        #pragma unroll
        for (int nt = 0; nt < 4; ++nt) {
            const int n0 = nt * 16;
            f32x4 acc = {0.f, 0.f, 0.f, 0.f};
            acc = __builtin_amdgcn_mfma_f32_16x16x32_bf16(w16a[nt], g0, acc, 0, 0, 0);
            acc = __builtin_amdgcn_mfma_f32_16x16x32_bf16(w16b[nt], g1, acc, 0, 0, 0);
            const float4 bs = b16v[nt];
            float4 ov;
            ov.x = acc[0] + bs.x;
            ov.y = acc[1] + bs.y;
            ov.z = acc[2] + bs.z;
            ov.w = acc[3] + bs.w;
            *reinterpret_cast<float4*>(&Out[ob + n0 + 4 * quad]) = ov;
        }
    }
}

extern "C" void kernel_launch(void* const* d_in, const int* in_sizes, int n_in,
                              void* d_out, int out_size, void* d_ws, size_t ws_size,
                              hipStream_t stream)
{
    (void)in_sizes; (void)n_in; (void)out_size; (void)ws_size;
    const float* X   = (const float*)d_in[0];
    const float* STE = (const float*)d_in[1];
    const float* W12 = (const float*)d_in[2];
    const float* b12 = (const float*)d_in[3];
    const float* W13 = (const float*)d_in[4];
    const float* b13 = (const float*)d_in[5];
    const float* W14 = (const float*)d_in[6];
    const float* b14 = (const float*)d_in[7];
    const float* W15 = (const float*)d_in[8];
    const float* b15 = (const float*)d_in[9];
    const float* W16 = (const float*)d_in[10];
    const float* b16 = (const float*)d_in[11];
    float* Out = (float*)d_out;
    __bf16* ws = (__bf16*)d_ws;   // needs 65,536 B

    hipLaunchKernelGGL(convert_weights, dim3(128), dim3(256), 0, stream,
                       W12, W13, W14, W15, W16, ws);
    hipLaunchKernelGGL(tam_fused, dim3(Bn * Nn), dim3(256), 0, stream,
                       X, STE, b12, b13, b14, b15, b16, ws, Out);
}

// Round 7
// 253.063 us; speedup vs baseline: 1.1148x; 1.1148x over previous
//
#include <hip/hip_runtime.h>
#include <hip/hip_bf16.h>

// Problem constants (fixed by reference)
#define Bn 16
#define Tn 64
#define Nn 256
#define Kn 8
#define dn 8
#define Dn 64
#define TDn 128   // 2*D

typedef __bf16 bf16x8 __attribute__((ext_vector_type(8)));
typedef __bf16 bf16x4 __attribute__((ext_vector_type(4)));
typedef float  f32x4  __attribute__((ext_vector_type(4)));
typedef float  f32x16 __attribute__((ext_vector_type(16)));

#if __has_builtin(__builtin_amdgcn_exp2f)
#define EXP2F(x) __builtin_amdgcn_exp2f(x)
#else
#define EXP2F(x) exp2f(x)
#endif

#if __has_builtin(__builtin_amdgcn_rcpf)
#define RCPF(x) __builtin_amdgcn_rcpf(x)
#else
#define RCPF(x) (1.0f / (x))
#endif

// tanh-form GELU via native exp2 + rcp (~10 VALU ops vs ~60 for libm erff).
__device__ __forceinline__ float geluf(float x) {
    const float x2 = x * x;
    const float v = x * fmaf(0.10294342f, x2, 2.30220920f);   // 2*log2e*0.79788456*(x+0.044715x^3)
    const float w = EXP2F(-fabsf(v));
    const float r = RCPF(1.0f + w);
    const float t = (1.0f - w) * r;                            // tanh(|u|)
    return fmaf(0.5f * fabsf(x), t, 0.5f * x);
}

__device__ __forceinline__ bf16x8 bzero8() {
    bf16x8 z;
    #pragma unroll
    for (int e = 0; e < 8; ++e) z[e] = (__bf16)0.0f;
    return z;
}

__device__ __forceinline__ bf16x8 pack8(float4 f0, float4 f1) {
    bf16x8 a;
    a[0] = (__bf16)f0.x; a[1] = (__bf16)f0.y;
    a[2] = (__bf16)f0.z; a[3] = (__bf16)f0.w;
    a[4] = (__bf16)f1.x; a[5] = (__bf16)f1.y;
    a[6] = (__bf16)f1.z; a[7] = (__bf16)f1.w;
    return a;
}

// ---- Kernel 1: convert all weights fp32 -> bf16 into d_ws ----
// ws layout (bf16): [0,24576) Wqkv rows 0-63=W12,64-127=W13,128-191=W14 (row=128 k)
//                   [24576,28672) W15 [64][64]; [28672,32768) W16 [64][64]
__global__ void convert_weights(const float* __restrict__ W12, const float* __restrict__ W13,
                                const float* __restrict__ W14, const float* __restrict__ W15,
                                const float* __restrict__ W16, __bf16* __restrict__ ws)
{
    const int i = blockIdx.x * 256 + threadIdx.x;   // 0..32767
    float v;
    if      (i < 8192)  v = W12[i];
    else if (i < 16384) v = W13[i - 8192];
    else if (i < 24576) v = W14[i - 16384];
    else if (i < 28672) v = W15[i - 24576];
    else                v = W16[i - 28672];
    ws[i] = (__bf16)v;
}

// ---- Kernel 2: fused block per (b, n-pair); 256 threads = 4 waves ----
// R7: TWO n-columns per block (n0, n0+1), interleaved at source level at every step.
// R4/R5/R6 all pinned at ~160us despite occupancy/conflict/prefetch changes -> the
// limiter is synchronized stall generations with no intra-wave ILP. Dual independent
// chains per wave fill each other's latency gaps; weight loads amortized 2x.
// LDS 55,296 B -> 2 blocks/CU (8 waves). TLP (proven useless, R5) traded for ILP.
// Per-col regions (c*27648): vt[64][72] | qs[64][72] (+9216) | ks[64][72] (+18432).
// Phases 2/4 swapped-operand MFMA (D = W.H^T) -> b64/dwordx4 epilogues.
// Phase 3: 32x32x16 MFMA, P in registers (lane^32 swap repack).
__global__ __launch_bounds__(256, 2)
void tam_fused(const float* __restrict__ X,
               const float* __restrict__ STE,
               const float* __restrict__ b12, const float* __restrict__ b13,
               const float* __restrict__ b14, const float* __restrict__ b15,
               const float* __restrict__ b16,
               const __bf16* __restrict__ Wb,   // converted weights in ws
               float* __restrict__ Out)
{
    __shared__ __align__(16) char smem[55296];
    __bf16 (*vtP[2])[72] = { reinterpret_cast<__bf16 (*)[72]>(smem),
                             reinterpret_cast<__bf16 (*)[72]>(smem + 27648) };
    __bf16 (*qsP[2])[72] = { reinterpret_cast<__bf16 (*)[72]>(smem + 9216),
                             reinterpret_cast<__bf16 (*)[72]>(smem + 27648 + 9216) };
    __bf16 (*ksP[2])[72] = { reinterpret_cast<__bf16 (*)[72]>(smem + 18432),
                             reinterpret_cast<__bf16 (*)[72]>(smem + 27648 + 18432) };

    const int bn   = blockIdx.x;   // 0..2047
    const int b    = bn >> 7;      // / 128 pairs
    const int n0   = (bn & 127) * 2;
    const int tid  = threadIdx.x;
    const int lane = tid & 63;
    const int wv   = __builtin_amdgcn_readfirstlane(tid >> 6);
    const int cl   = lane & 15;          // 16x16 MFMA col-in-tile / A-row-in-tile
    const int quad = lane >> 4;
    const int kb   = quad * 8;           // 16x16 MFMA k-offset
    const int m0   = wv * 16;            // this wave's row-tile

    const __bf16* Wqkv = Wb;             // [192][128]
    const __bf16* W15b = Wb + 24576;     // [64][64]
    const __bf16* W16b = Wb + 28672;     // [64][64]

    // ---------------- Phase 2: qkv = gelu(H @ Wqkv^T + b), dual-column ----------------
    // q/k swapped operands (D[feat][t]); v unswapped (D[t][feat]) feeding transposed vt.
    // q pre-scaled by 1/sqrt(8)*log2(e). Weight frags shared across both columns.
    {
        bf16x8 af[2][4];
        {
            const int t = m0 + cl;
            const size_t rb = (((size_t)b * Tn + t) * Nn + n0) * (size_t)Dn;
            #pragma unroll
            for (int c = 0; c < 2; ++c) {
                const float4* Xr = reinterpret_cast<const float4*>(X + rb + c * Dn);
                const float4* Sr = reinterpret_cast<const float4*>(STE + rb + c * Dn);
                const int fi = quad * 2;
                const float4 x0 = Xr[fi], x1 = Xr[fi + 1];
                const float4 x2 = Xr[8 + fi], x3 = Xr[8 + fi + 1];
                const float4 s0 = Sr[fi], s1 = Sr[fi + 1];
                const float4 s2 = Sr[8 + fi], s3 = Sr[8 + fi + 1];
                af[c][0] = pack8(x0, x1);
                af[c][1] = pack8(x2, x3);
                af[c][2] = pack8(s0, s1);
                af[c][3] = pack8(s2, s3);
            }
        }

        #pragma unroll
        for (int nt = 0; nt < 12; ++nt) {
            const int nf = nt * 16;
            bf16x8 wq[4];
            #pragma unroll
            for (int kk = 0; kk < 4; ++kk)
                wq[kk] = *reinterpret_cast<const bf16x8*>(&Wqkv[(nf + cl) * TDn + kk * 32 + kb]);
            f32x4 acc[2] = { {0.f, 0.f, 0.f, 0.f}, {0.f, 0.f, 0.f, 0.f} };
            if (nt < 8) {
                // swapped: D = W.H^T -> row = feat nf+4q+r, col = t m0+cl
                #pragma unroll
                for (int kk = 0; kk < 4; ++kk) {
                    #pragma unroll
                    for (int c = 0; c < 2; ++c)
                        acc[c] = __builtin_amdgcn_mfma_f32_16x16x32_bf16(wq[kk], af[c][kk], acc[c], 0, 0, 0);
                }
                if (nt < 4) {
                    const float4 bs = *reinterpret_cast<const float4*>(&b12[nf + 4 * quad]);
                    #pragma unroll
                    for (int c = 0; c < 2; ++c) {
                        bf16x4 pk;
                        pk[0] = (__bf16)(geluf(acc[c][0] + bs.x) * 0.51006951f);
                        pk[1] = (__bf16)(geluf(acc[c][1] + bs.y) * 0.51006951f);
                        pk[2] = (__bf16)(geluf(acc[c][2] + bs.z) * 0.51006951f);
                        pk[3] = (__bf16)(geluf(acc[c][3] + bs.w) * 0.51006951f);
                        *reinterpret_cast<bf16x4*>(&qsP[c][m0 + cl][nf + 4 * quad]) = pk;
                    }
                } else {
                    const float4 bs = *reinterpret_cast<const float4*>(&b13[nf - 64 + 4 * quad]);
                    #pragma unroll
                    for (int c = 0; c < 2; ++c) {
                        bf16x4 pk;
                        pk[0] = (__bf16)geluf(acc[c][0] + bs.x);
                        pk[1] = (__bf16)geluf(acc[c][1] + bs.y);
                        pk[2] = (__bf16)geluf(acc[c][2] + bs.z);
                        pk[3] = (__bf16)geluf(acc[c][3] + bs.w);
                        *reinterpret_cast<bf16x4*>(&ksP[c][m0 + cl][nf - 64 + 4 * quad]) = pk;
                    }
                }
            } else {
                // unswapped: D = H.W^T -> row = t m0+4q+r, col = feat nf-128+cl
                #pragma unroll
                for (int kk = 0; kk < 4; ++kk) {
                    #pragma unroll
                    for (int c = 0; c < 2; ++c)
                        acc[c] = __builtin_amdgcn_mfma_f32_16x16x32_bf16(af[c][kk], wq[kk], acc[c], 0, 0, 0);
                }
                const float vbias = b14[nf - 128 + cl];
                #pragma unroll
                for (int c = 0; c < 2; ++c) {
                    bf16x4 pv;
                    #pragma unroll
                    for (int r = 0; r < 4; ++r) pv[r] = (__bf16)geluf(acc[c][r] + vbias);
                    // col = h*8+d; rows m0+4q..+3 consecutive t -> contiguous in vt[col][t]
                    *reinterpret_cast<bf16x4*>(&vtP[c][nf - 128 + cl][m0 + 4 * quad]) = pv;
                }
            }
        }
    }
    __syncthreads();

    // ---------------- Phase 3: 32x32x16 MFMA attention, dual-column, P in registers -------
    // Wave wv owns heads {2wv, 2wv+1} (columns [16wv,16wv+16) of qs/ks/vt) in BOTH n-cols:
    // column-disjoint across waves -> no internal barriers.
    //   A: row = lane&31, k = (lane>>5)*8 + e;  B: col = lane&31, k = (lane>>5)*8 + e
    //   C: col = lane&31, row = (reg&3) + 8*(reg>>2) + 4*(lane>>5)
    {
        const int half = lane >> 5;
        const int l31  = lane & 31;

        for (int hh = 0; hh < 2; ++hh) {
            const int hc = 8 * (2 * wv + hh);

            bf16x8 kA0[2], kA1[2], qB0[2], qB1[2], vA0[2], vA1[2];
            #pragma unroll
            for (int c = 0; c < 2; ++c) {
                kA0[c] = bzero8(); kA1[c] = bzero8(); qB0[c] = bzero8(); qB1[c] = bzero8();
                vA0[c] = bzero8(); vA1[c] = bzero8();
                if (half == 0) {
                    kA0[c] = *reinterpret_cast<const bf16x8*>(&ksP[c][ 0 + l31][hc]);
                    kA1[c] = *reinterpret_cast<const bf16x8*>(&ksP[c][32 + l31][hc]);
                    qB0[c] = *reinterpret_cast<const bf16x8*>(&qsP[c][ 0 + l31][hc]);
                    qB1[c] = *reinterpret_cast<const bf16x8*>(&qsP[c][32 + l31][hc]);
                }
                if (l31 < 8) {
                    vA0[c] = *reinterpret_cast<const bf16x8*>(&vtP[c][hc + l31][ 0 + 8 * half]);
                    vA1[c] = *reinterpret_cast<const bf16x8*>(&vtP[c][hc + l31][16 + 8 * half]);
                }
            }

            f32x16 zc16;
            #pragma unroll
            for (int r = 0; r < 16; ++r) zc16[r] = 0.f;

            // ================= tq-tile 0 (tq = l31; tk-tile 0 only, causal) =================
            {
                f32x16 S[2];
                #pragma unroll
                for (int c = 0; c < 2; ++c)
                    S[c] = __builtin_amdgcn_mfma_f32_32x32x16_bf16(kA0[c], qB0[c], zc16, 0, 0, 0);
                #pragma unroll
                for (int r = 0; r < 16; ++r) {
                    const int tk = (r & 3) + 8 * (r >> 2) + 4 * half;
                    #pragma unroll
                    for (int c = 0; c < 2; ++c) S[c][r] = (tk > l31) ? -3.0e38f : S[c][r];
                }
                float mx[2] = { S[0][0], S[1][0] };
                #pragma unroll
                for (int r = 1; r < 16; ++r) {
                    #pragma unroll
                    for (int c = 0; c < 2; ++c) mx[c] = fmaxf(mx[c], S[c][r]);
                }
                #pragma unroll
                for (int c = 0; c < 2; ++c) mx[c] = fmaxf(mx[c], __shfl_xor(mx[c], 32));
                float sum[2] = { 0.f, 0.f };
                #pragma unroll
                for (int r = 0; r < 16; ++r) {
                    #pragma unroll
                    for (int c = 0; c < 2; ++c) {
                        const float p = EXP2F(S[c][r] - mx[c]);
                        S[c][r] = p; sum[c] += p;
                    }
                }
                #pragma unroll
                for (int c = 0; c < 2; ++c) sum[c] += __shfl_xor(sum[c], 32);

                unsigned u[2][8];
                #pragma unroll
                for (int i = 0; i < 8; ++i) {
                    #pragma unroll
                    for (int c = 0; c < 2; ++c) {
                        union { __bf16 h[2]; unsigned w; } cv;
                        cv.h[0] = (__bf16)S[c][2 * i]; cv.h[1] = (__bf16)S[c][2 * i + 1];
                        u[c][i] = cv.w;
                    }
                }
                f32x16 O[2] = { zc16, zc16 };
                #pragma unroll
                for (int ch = 0; ch < 2; ++ch) {
                    #pragma unroll
                    for (int c = 0; c < 2; ++c) {
                        const unsigned x0 = __shfl_xor(u[c][4 * ch + 0], 32);
                        const unsigned x1 = __shfl_xor(u[c][4 * ch + 1], 32);
                        const unsigned x2 = __shfl_xor(u[c][4 * ch + 2], 32);
                        const unsigned x3 = __shfl_xor(u[c][4 * ch + 3], 32);
                        union { unsigned w[4]; bf16x8 v; } bw;
                        bw.w[0] = half ? x2 : u[c][4 * ch + 0];
                        bw.w[1] = half ? x3 : u[c][4 * ch + 1];
                        bw.w[2] = half ? u[c][4 * ch + 2] : x0;
                        bw.w[3] = half ? u[c][4 * ch + 3] : x1;
                        O[c] = __builtin_amdgcn_mfma_f32_32x32x16_bf16(ch ? vA1[c] : vA0[c],
                                                                       bw.v, O[c], 0, 0, 0);
                    }
                }
                #pragma unroll
                for (int c = 0; c < 2; ++c) {
                    const float inv = RCPF(sum[c]);
                    bf16x4 ov;
                    #pragma unroll
                    for (int r = 0; r < 4; ++r) ov[r] = (__bf16)(O[c][r] * inv);
                    *reinterpret_cast<bf16x4*>(&qsP[c][l31][hc + 4 * half]) = ov;
                }
            }

            // ================= tq-tile 1 (tq = 32+l31; tk-tiles 0 and 1) =================
            {
                bf16x8 vA2[2], vA3[2];
                #pragma unroll
                for (int c = 0; c < 2; ++c) {
                    vA2[c] = bzero8(); vA3[c] = bzero8();
                    if (l31 < 8) {
                        vA2[c] = *reinterpret_cast<const bf16x8*>(&vtP[c][hc + l31][32 + 8 * half]);
                        vA3[c] = *reinterpret_cast<const bf16x8*>(&vtP[c][hc + l31][48 + 8 * half]);
                    }
                }
                f32x16 Sa[2], Sb[2];
                #pragma unroll
                for (int c = 0; c < 2; ++c) {
                    Sa[c] = __builtin_amdgcn_mfma_f32_32x32x16_bf16(kA0[c], qB1[c], zc16, 0, 0, 0);
                    Sb[c] = __builtin_amdgcn_mfma_f32_32x32x16_bf16(kA1[c], qB1[c], zc16, 0, 0, 0);
                }
                #pragma unroll
                for (int r = 0; r < 16; ++r) {   // mask only the diagonal tile (tk 32..63)
                    const int tk = (r & 3) + 8 * (r >> 2) + 4 * half;
                    #pragma unroll
                    for (int c = 0; c < 2; ++c) Sb[c][r] = (tk > l31) ? -3.0e38f : Sb[c][r];
                }
                float mx[2] = { Sa[0][0], Sa[1][0] };
                #pragma unroll
                for (int r = 1; r < 16; ++r) {
                    #pragma unroll
                    for (int c = 0; c < 2; ++c) mx[c] = fmaxf(mx[c], Sa[c][r]);
                }
                #pragma unroll
                for (int r = 0; r < 16; ++r) {
                    #pragma unroll
                    for (int c = 0; c < 2; ++c) mx[c] = fmaxf(mx[c], Sb[c][r]);
                }
                #pragma unroll
                for (int c = 0; c < 2; ++c) mx[c] = fmaxf(mx[c], __shfl_xor(mx[c], 32));
                float sum[2] = { 0.f, 0.f };
                #pragma unroll
                for (int r = 0; r < 16; ++r) {
                    #pragma unroll
                    for (int c = 0; c < 2; ++c) {
                        const float p = EXP2F(Sa[c][r] - mx[c]); Sa[c][r] = p; sum[c] += p;
                    }
                }
                #pragma unroll
                for (int r = 0; r < 16; ++r) {
                    #pragma unroll
                    for (int c = 0; c < 2; ++c) {
                        const float p = EXP2F(Sb[c][r] - mx[c]); Sb[c][r] = p; sum[c] += p;
                    }
                }
                #pragma unroll
                for (int c = 0; c < 2; ++c) sum[c] += __shfl_xor(sum[c], 32);

                unsigned ua[2][8], ub[2][8];
                #pragma unroll
                for (int i = 0; i < 8; ++i) {
                    #pragma unroll
                    for (int c = 0; c < 2; ++c) {
                        union { __bf16 h[2]; unsigned w; } cv;
                        cv.h[0] = (__bf16)Sa[c][2 * i]; cv.h[1] = (__bf16)Sa[c][2 * i + 1];
                        ua[c][i] = cv.w;
                        union { __bf16 h[2]; unsigned w; } cw;
                        cw.h[0] = (__bf16)Sb[c][2 * i]; cw.h[1] = (__bf16)Sb[c][2 * i + 1];
                        ub[c][i] = cw.w;
                    }
                }
                f32x16 O[2] = { zc16, zc16 };
                #pragma unroll
                for (int ch = 0; ch < 4; ++ch) {
                    const int c2 = ch & 1;
                    #pragma unroll
                    for (int c = 0; c < 2; ++c) {
                        const unsigned* uu = (ch < 2) ? ua[c] : ub[c];
                        const unsigned x0 = __shfl_xor(uu[4 * c2 + 0], 32);
                        const unsigned x1 = __shfl_xor(uu[4 * c2 + 1], 32);
                        const unsigned x2 = __shfl_xor(uu[4 * c2 + 2], 32);
                        const unsigned x3 = __shfl_xor(uu[4 * c2 + 3], 32);
                        union { unsigned w[4]; bf16x8 v; } bw;
                        bw.w[0] = half ? x2 : uu[4 * c2 + 0];
                        bw.w[1] = half ? x3 : uu[4 * c2 + 1];
                        bw.w[2] = half ? uu[4 * c2 + 2] : x0;
                        bw.w[3] = half ? uu[4 * c2 + 3] : x1;
                        const bf16x8 vA = (ch == 0) ? vA0[c] : (ch == 1) ? vA1[c]
                                        : (ch == 2) ? vA2[c] : vA3[c];
                        O[c] = __builtin_amdgcn_mfma_f32_32x32x16_bf16(vA, bw.v, O[c], 0, 0, 0);
                    }
                }
                #pragma unroll
                for (int c = 0; c < 2; ++c) {
                    const float inv = RCPF(sum[c]);
                    bf16x4 ov;
                    #pragma unroll
                    for (int r = 0; r < 4; ++r) ov[r] = (__bf16)(O[c][r] * inv);
                    *reinterpret_cast<bf16x4*>(&qsP[c][32 + l31][hc + 4 * half]) = ov;
                }
            }
        }
    }
    __syncthreads();

    // ---------------- Phase 4: MLP, dual-column, shared weight frags ----------------
    {
        bf16x8 h0[2], h1[2];
        #pragma unroll
        for (int c = 0; c < 2; ++c) {
            h0[c] = *reinterpret_cast<const bf16x8*>(&qsP[c][m0 + cl][kb]);
            h1[c] = *reinterpret_cast<const bf16x8*>(&qsP[c][m0 + cl][32 + kb]);
        }
        // 4a: hidden = gelu(attn_out @ W15^T + b15) -> ks (swapped: D[feat][t], b64 stores)
        #pragma unroll
        for (int nt = 0; nt < 4; ++nt) {
            const int nf = nt * 16;
            const bf16x8 w0 = *reinterpret_cast<const bf16x8*>(&W15b[(nf + cl) * Dn + kb]);
            const bf16x8 w1 = *reinterpret_cast<const bf16x8*>(&W15b[(nf + cl) * Dn + 32 + kb]);
            const float4 bs = *reinterpret_cast<const float4*>(&b15[nf + 4 * quad]);
            #pragma unroll
            for (int c = 0; c < 2; ++c) {
                f32x4 acc = {0.f, 0.f, 0.f, 0.f};
                acc = __builtin_amdgcn_mfma_f32_16x16x32_bf16(w0, h0[c], acc, 0, 0, 0);
                acc = __builtin_amdgcn_mfma_f32_16x16x32_bf16(w1, h1[c], acc, 0, 0, 0);
                bf16x4 pk;
                pk[0] = (__bf16)geluf(acc[0] + bs.x);
                pk[1] = (__bf16)geluf(acc[1] + bs.y);
                pk[2] = (__bf16)geluf(acc[2] + bs.z);
                pk[3] = (__bf16)geluf(acc[3] + bs.w);
                *reinterpret_cast<bf16x4*>(&ksP[c][m0 + cl][nf + 4 * quad]) = pk;
            }
        }
        // No barrier: 4b reads only this wave's 16 rows of ks (same-wave DS in-order).
        bf16x8 g0[2], g1[2];
        #pragma unroll
        for (int c = 0; c < 2; ++c) {
            g0[c] = *reinterpret_cast<const bf16x8*>(&ksP[c][m0 + cl][kb]);
            g1[c] = *reinterpret_cast<const bf16x8*>(&ksP[c][m0 + cl][32 + kb]);
        }
        const size_t ob = (((size_t)(b * Tn + m0 + cl)) * Nn + n0) * (size_t)Dn;
        #pragma unroll
        for (int nt = 0; nt < 4; ++nt) {
            const int nf = nt * 16;
            const bf16x8 w0 = *reinterpret_cast<const bf16x8*>(&W16b[(nf + cl) * Dn + kb]);
            const bf16x8 w1 = *reinterpret_cast<const bf16x8*>(&W16b[(nf + cl) * Dn + 32 + kb]);
            const float4 bs = *reinterpret_cast<const float4*>(&b16[nf + 4 * quad]);
            #pragma unroll
            for (int c = 0; c < 2; ++c) {
                f32x4 acc = {0.f, 0.f, 0.f, 0.f};
                acc = __builtin_amdgcn_mfma_f32_16x16x32_bf16(w0, g0[c], acc, 0, 0, 0);
                acc = __builtin_amdgcn_mfma_f32_16x16x32_bf16(w1, g1[c], acc, 0, 0, 0);
                float4 ov;
                ov.x = acc[0] + bs.x;
                ov.y = acc[1] + bs.y;
                ov.z = acc[2] + bs.z;
                ov.w = acc[3] + bs.w;
                *reinterpret_cast<float4*>(&Out[ob + (size_t)c * Dn + nf + 4 * quad]) = ov;
            }
        }
    }
}

extern "C" void kernel_launch(void* const* d_in, const int* in_sizes, int n_in,
                              void* d_out, int out_size, void* d_ws, size_t ws_size,
                              hipStream_t stream)
{
    (void)in_sizes; (void)n_in; (void)out_size; (void)ws_size;
    const float* X   = (const float*)d_in[0];
    const float* STE = (const float*)d_in[1];
    const float* W12 = (const float*)d_in[2];
    const float* b12 = (const float*)d_in[3];
    const float* W13 = (const float*)d_in[4];
    const float* b13 = (const float*)d_in[5];
    const float* W14 = (const float*)d_in[6];
    const float* b14 = (const float*)d_in[7];
    const float* W15 = (const float*)d_in[8];
    const float* b15 = (const float*)d_in[9];
    const float* W16 = (const float*)d_in[10];
    const float* b16 = (const float*)d_in[11];
    float* Out = (float*)d_out;
    __bf16* ws = (__bf16*)d_ws;   // needs 65,536 B

    hipLaunchKernelGGL(convert_weights, dim3(128), dim3(256), 0, stream,
                       W12, W13, W14, W15, W16, ws);
    hipLaunchKernelGGL(tam_fused, dim3(Bn * Nn / 2), dim3(256), 0, stream,
                       X, STE, b12, b13, b14, b15, b16, ws, Out);
}

// Round 9
// 245.665 us; speedup vs baseline: 1.1484x; 1.0301x over previous
//
#include <hip/hip_runtime.h>
#include <hip/hip_bf16.h>

// Problem constants (fixed by reference)
#define Bn 16
#define Tn 64
#define Nn 256
#define Kn 8
#define dn 8
#define Dn 64
#define TDn 128   // 2*D

typedef __bf16 bf16x8 __attribute__((ext_vector_type(8)));
typedef __bf16 bf16x4 __attribute__((ext_vector_type(4)));
typedef float  f32x4  __attribute__((ext_vector_type(4)));
typedef float  f32x16 __attribute__((ext_vector_type(16)));

#if __has_builtin(__builtin_amdgcn_exp2f)
#define EXP2F(x) __builtin_amdgcn_exp2f(x)
#else
#define EXP2F(x) exp2f(x)
#endif

#if __has_builtin(__builtin_amdgcn_rcpf)
#define RCPF(x) __builtin_amdgcn_rcpf(x)
#else
#define RCPF(x) (1.0f / (x))
#endif

// tanh-form GELU via native exp2 + rcp (~10 VALU ops vs ~60 for libm erff).
__device__ __forceinline__ float geluf(float x) {
    const float x2 = x * x;
    const float v = x * fmaf(0.10294342f, x2, 2.30220920f);   // 2*log2e*0.79788456*(x+0.044715x^3)
    const float w = EXP2F(-fabsf(v));
    const float r = RCPF(1.0f + w);
    const float t = (1.0f - w) * r;                            // tanh(|u|)
    return fmaf(0.5f * fabsf(x), t, 0.5f * x);
}

__device__ __forceinline__ bf16x8 bzero8() {
    bf16x8 z;
    #pragma unroll
    for (int e = 0; e < 8; ++e) z[e] = (__bf16)0.0f;
    return z;
}

__device__ __forceinline__ bf16x8 pack8(float4 f0, float4 f1) {
    bf16x8 a;
    a[0] = (__bf16)f0.x; a[1] = (__bf16)f0.y;
    a[2] = (__bf16)f0.z; a[3] = (__bf16)f0.w;
    a[4] = (__bf16)f1.x; a[5] = (__bf16)f1.y;
    a[6] = (__bf16)f1.z; a[7] = (__bf16)f1.w;
    return a;
}

// Swizzled LDS addressing: logical [64][64] bf16 tile stored at stride 128 B with
// byte ^= (row&7)<<4. Rows exactly 128 B (no pad); XOR is a multiple of 16 so b64/b128
// alignment is preserved; fixed-column reads across rows spread over 8 16-B slots
// (~4-way conflict, same as the old stride-72 pad, at 8704->8192 B per buffer).
__device__ __forceinline__ char* ldsp(char* base, int row, int col) {
    return base + (((row << 7) + (col << 1)) ^ ((row & 7) << 4));
}

// ---- Kernel 1: convert all weights fp32 -> bf16 into d_ws ----
// ws layout (bf16): [0,24576) Wqkv rows 0-63=W12,64-127=W13,128-191=W14 (row=128 k)
//                   [24576,28672) W15 [64][64]; [28672,32768) W16 [64][64]
__global__ void convert_weights(const float* __restrict__ W12, const float* __restrict__ W13,
                                const float* __restrict__ W14, const float* __restrict__ W15,
                                const float* __restrict__ W16, __bf16* __restrict__ ws)
{
    const int i = blockIdx.x * 256 + threadIdx.x;   // 0..32767
    float v;
    if      (i < 8192)  v = W12[i];
    else if (i < 16384) v = W13[i - 8192];
    else if (i < 24576) v = W14[i - 16384];
    else if (i < 28672) v = W15[i - 24576];
    else                v = W16[i - 28672];
    ws[i] = (__bf16)v;
}

// ---- Kernel 2: fused block per (b, n-pair); 256 threads = 4 waves ----
// R8 (resubmit; R8 bench was an infra failure, never ran): R7's dual-column ILP
// structure, LDS re-laid-out with XOR swizzle instead of pad: 55,296 -> 49,152 B ->
// 3 blocks/CU (12 waves, was 2 blocks/8 waves). Single variable change vs R7 to
// convert the proven ILP win into higher wave-level overlap.
// Per-col regions (c*24576): vt | qs (+8192) | ks (+16384), each swizzled [64][64].
// Phases 2/4 swapped-operand MFMA (D = W.H^T) -> b64/dwordx4 epilogues.
// Phase 3: 32x32x16 MFMA, P in registers (lane^32 swap repack).
__global__ __launch_bounds__(256, 3)
void tam_fused(const float* __restrict__ X,
               const float* __restrict__ STE,
               const float* __restrict__ b12, const float* __restrict__ b13,
               const float* __restrict__ b14, const float* __restrict__ b15,
               const float* __restrict__ b16,
               const __bf16* __restrict__ Wb,   // converted weights in ws
               float* __restrict__ Out)
{
    __shared__ __align__(16) char smem[49152];
    char* const vtb[2] = { smem,         smem + 24576 };
    char* const qsb[2] = { smem + 8192,  smem + 24576 + 8192 };
    char* const ksb[2] = { smem + 16384, smem + 24576 + 16384 };

    const int bn   = blockIdx.x;   // 0..2047
    const int b    = bn >> 7;      // / 128 pairs
    const int n0   = (bn & 127) * 2;
    const int tid  = threadIdx.x;
    const int lane = tid & 63;
    const int wv   = __builtin_amdgcn_readfirstlane(tid >> 6);
    const int cl   = lane & 15;          // 16x16 MFMA col-in-tile / A-row-in-tile
    const int quad = lane >> 4;
    const int kb   = quad * 8;           // 16x16 MFMA k-offset
    const int m0   = wv * 16;            // this wave's row-tile

    const __bf16* Wqkv = Wb;             // [192][128]
    const __bf16* W15b = Wb + 24576;     // [64][64]
    const __bf16* W16b = Wb + 28672;     // [64][64]

    // ---------------- Phase 2: qkv = gelu(H @ Wqkv^T + b), dual-column ----------------
    // q/k swapped operands (D[feat][t]); v unswapped (D[t][feat]) feeding transposed vt.
    // q pre-scaled by 1/sqrt(8)*log2(e). Weight frags shared across both columns.
    {
        bf16x8 af[2][4];
        {
            const int t = m0 + cl;
            const size_t rb = (((size_t)b * Tn + t) * Nn + n0) * (size_t)Dn;
            #pragma unroll
            for (int c = 0; c < 2; ++c) {
                const float4* Xr = reinterpret_cast<const float4*>(X + rb + c * Dn);
                const float4* Sr = reinterpret_cast<const float4*>(STE + rb + c * Dn);
                const int fi = quad * 2;
                const float4 x0 = Xr[fi], x1 = Xr[fi + 1];
                const float4 x2 = Xr[8 + fi], x3 = Xr[8 + fi + 1];
                const float4 s0 = Sr[fi], s1 = Sr[fi + 1];
                const float4 s2 = Sr[8 + fi], s3 = Sr[8 + fi + 1];
                af[c][0] = pack8(x0, x1);
                af[c][1] = pack8(x2, x3);
                af[c][2] = pack8(s0, s1);
                af[c][3] = pack8(s2, s3);
            }
        }

        #pragma unroll
        for (int nt = 0; nt < 12; ++nt) {
            const int nf = nt * 16;
            bf16x8 wq[4];
            #pragma unroll
            for (int kk = 0; kk < 4; ++kk)
                wq[kk] = *reinterpret_cast<const bf16x8*>(&Wqkv[(nf + cl) * TDn + kk * 32 + kb]);
            f32x4 acc[2] = { {0.f, 0.f, 0.f, 0.f}, {0.f, 0.f, 0.f, 0.f} };
            if (nt < 8) {
                // swapped: D = W.H^T -> row = feat nf+4q+r, col = t m0+cl
                #pragma unroll
                for (int kk = 0; kk < 4; ++kk) {
                    #pragma unroll
                    for (int c = 0; c < 2; ++c)
                        acc[c] = __builtin_amdgcn_mfma_f32_16x16x32_bf16(wq[kk], af[c][kk], acc[c], 0, 0, 0);
                }
                if (nt < 4) {
                    const float4 bs = *reinterpret_cast<const float4*>(&b12[nf + 4 * quad]);
                    #pragma unroll
                    for (int c = 0; c < 2; ++c) {
                        bf16x4 pk;
                        pk[0] = (__bf16)(geluf(acc[c][0] + bs.x) * 0.51006951f);
                        pk[1] = (__bf16)(geluf(acc[c][1] + bs.y) * 0.51006951f);
                        pk[2] = (__bf16)(geluf(acc[c][2] + bs.z) * 0.51006951f);
                        pk[3] = (__bf16)(geluf(acc[c][3] + bs.w) * 0.51006951f);
                        *reinterpret_cast<bf16x4*>(ldsp(qsb[c], m0 + cl, nf + 4 * quad)) = pk;
                    }
                } else {
                    const float4 bs = *reinterpret_cast<const float4*>(&b13[nf - 64 + 4 * quad]);
                    #pragma unroll
                    for (int c = 0; c < 2; ++c) {
                        bf16x4 pk;
                        pk[0] = (__bf16)geluf(acc[c][0] + bs.x);
                        pk[1] = (__bf16)geluf(acc[c][1] + bs.y);
                        pk[2] = (__bf16)geluf(acc[c][2] + bs.z);
                        pk[3] = (__bf16)geluf(acc[c][3] + bs.w);
                        *reinterpret_cast<bf16x4*>(ldsp(ksb[c], m0 + cl, nf - 64 + 4 * quad)) = pk;
                    }
                }
            } else {
                // unswapped: D = H.W^T -> row = t m0+4q+r, col = feat nf-128+cl
                #pragma unroll
                for (int kk = 0; kk < 4; ++kk) {
                    #pragma unroll
                    for (int c = 0; c < 2; ++c)
                        acc[c] = __builtin_amdgcn_mfma_f32_16x16x32_bf16(af[c][kk], wq[kk], acc[c], 0, 0, 0);
                }
                const float vbias = b14[nf - 128 + cl];
                #pragma unroll
                for (int c = 0; c < 2; ++c) {
                    bf16x4 pv;
                    #pragma unroll
                    for (int r = 0; r < 4; ++r) pv[r] = (__bf16)geluf(acc[c][r] + vbias);
                    // vt row = h*8+d (= nf-128+cl); cols m0+4q..+3 consecutive t
                    *reinterpret_cast<bf16x4*>(ldsp(vtb[c], nf - 128 + cl, m0 + 4 * quad)) = pv;
                }
            }
        }
    }
    __syncthreads();

    // ---------------- Phase 3: 32x32x16 MFMA attention, dual-column, P in registers -------
    // Wave wv owns heads {2wv, 2wv+1} (columns [16wv,16wv+16) of qs/ks/vt) in BOTH n-cols:
    // column-disjoint across waves -> no internal barriers.
    //   A: row = lane&31, k = (lane>>5)*8 + e;  B: col = lane&31, k = (lane>>5)*8 + e
    //   C: col = lane&31, row = (reg&3) + 8*(reg>>2) + 4*(lane>>5)
    {
        const int half = lane >> 5;
        const int l31  = lane & 31;

        for (int hh = 0; hh < 2; ++hh) {
            const int hc = 8 * (2 * wv + hh);

            bf16x8 kA0[2], kA1[2], qB0[2], qB1[2], vA0[2], vA1[2];
            #pragma unroll
            for (int c = 0; c < 2; ++c) {
                kA0[c] = bzero8(); kA1[c] = bzero8(); qB0[c] = bzero8(); qB1[c] = bzero8();
                vA0[c] = bzero8(); vA1[c] = bzero8();
                if (half == 0) {
                    kA0[c] = *reinterpret_cast<const bf16x8*>(ldsp(ksb[c],  0 + l31, hc));
                    kA1[c] = *reinterpret_cast<const bf16x8*>(ldsp(ksb[c], 32 + l31, hc));
                    qB0[c] = *reinterpret_cast<const bf16x8*>(ldsp(qsb[c],  0 + l31, hc));
                    qB1[c] = *reinterpret_cast<const bf16x8*>(ldsp(qsb[c], 32 + l31, hc));
                }
                if (l31 < 8) {
                    vA0[c] = *reinterpret_cast<const bf16x8*>(ldsp(vtb[c], hc + l31,  0 + 8 * half));
                    vA1[c] = *reinterpret_cast<const bf16x8*>(ldsp(vtb[c], hc + l31, 16 + 8 * half));
                }
            }

            f32x16 zc16;
            #pragma unroll
            for (int r = 0; r < 16; ++r) zc16[r] = 0.f;

            // ================= tq-tile 0 (tq = l31; tk-tile 0 only, causal) =================
            {
                f32x16 S[2];
                #pragma unroll
                for (int c = 0; c < 2; ++c)
                    S[c] = __builtin_amdgcn_mfma_f32_32x32x16_bf16(kA0[c], qB0[c], zc16, 0, 0, 0);
                #pragma unroll
                for (int r = 0; r < 16; ++r) {
                    const int tk = (r & 3) + 8 * (r >> 2) + 4 * half;
                    #pragma unroll
                    for (int c = 0; c < 2; ++c) S[c][r] = (tk > l31) ? -3.0e38f : S[c][r];
                }
                float mx[2] = { S[0][0], S[1][0] };
                #pragma unroll
                for (int r = 1; r < 16; ++r) {
                    #pragma unroll
                    for (int c = 0; c < 2; ++c) mx[c] = fmaxf(mx[c], S[c][r]);
                }
                #pragma unroll
                for (int c = 0; c < 2; ++c) mx[c] = fmaxf(mx[c], __shfl_xor(mx[c], 32));
                float sum[2] = { 0.f, 0.f };
                #pragma unroll
                for (int r = 0; r < 16; ++r) {
                    #pragma unroll
                    for (int c = 0; c < 2; ++c) {
                        const float p = EXP2F(S[c][r] - mx[c]);
                        S[c][r] = p; sum[c] += p;
                    }
                }
                #pragma unroll
                for (int c = 0; c < 2; ++c) sum[c] += __shfl_xor(sum[c], 32);

                unsigned u[2][8];
                #pragma unroll
                for (int i = 0; i < 8; ++i) {
                    #pragma unroll
                    for (int c = 0; c < 2; ++c) {
                        union { __bf16 h[2]; unsigned w; } cv;
                        cv.h[0] = (__bf16)S[c][2 * i]; cv.h[1] = (__bf16)S[c][2 * i + 1];
                        u[c][i] = cv.w;
                    }
                }
                f32x16 O[2] = { zc16, zc16 };
                #pragma unroll
                for (int ch = 0; ch < 2; ++ch) {
                    #pragma unroll
                    for (int c = 0; c < 2; ++c) {
                        const unsigned x0 = __shfl_xor(u[c][4 * ch + 0], 32);
                        const unsigned x1 = __shfl_xor(u[c][4 * ch + 1], 32);
                        const unsigned x2 = __shfl_xor(u[c][4 * ch + 2], 32);
                        const unsigned x3 = __shfl_xor(u[c][4 * ch + 3], 32);
                        union { unsigned w[4]; bf16x8 v; } bw;
                        bw.w[0] = half ? x2 : u[c][4 * ch + 0];
                        bw.w[1] = half ? x3 : u[c][4 * ch + 1];
                        bw.w[2] = half ? u[c][4 * ch + 2] : x0;
                        bw.w[3] = half ? u[c][4 * ch + 3] : x1;
                        O[c] = __builtin_amdgcn_mfma_f32_32x32x16_bf16(ch ? vA1[c] : vA0[c],
                                                                       bw.v, O[c], 0, 0, 0);
                    }
                }
                #pragma unroll
                for (int c = 0; c < 2; ++c) {
                    const float inv = RCPF(sum[c]);
                    bf16x4 ov;
                    #pragma unroll
                    for (int r = 0; r < 4; ++r) ov[r] = (__bf16)(O[c][r] * inv);
                    *reinterpret_cast<bf16x4*>(ldsp(qsb[c], l31, hc + 4 * half)) = ov;
                }
            }

            // ================= tq-tile 1 (tq = 32+l31; tk-tiles 0 and 1) =================
            {
                bf16x8 vA2[2], vA3[2];
                #pragma unroll
                for (int c = 0; c < 2; ++c) {
                    vA2[c] = bzero8(); vA3[c] = bzero8();
                    if (l31 < 8) {
                        vA2[c] = *reinterpret_cast<const bf16x8*>(ldsp(vtb[c], hc + l31, 32 + 8 * half));
                        vA3[c] = *reinterpret_cast<const bf16x8*>(ldsp(vtb[c], hc + l31, 48 + 8 * half));
                    }
                }
                f32x16 Sa[2], Sb[2];
                #pragma unroll
                for (int c = 0; c < 2; ++c) {
                    Sa[c] = __builtin_amdgcn_mfma_f32_32x32x16_bf16(kA0[c], qB1[c], zc16, 0, 0, 0);
                    Sb[c] = __builtin_amdgcn_mfma_f32_32x32x16_bf16(kA1[c], qB1[c], zc16, 0, 0, 0);
                }
                #pragma unroll
                for (int r = 0; r < 16; ++r) {   // mask only the diagonal tile (tk 32..63)
                    const int tk = (r & 3) + 8 * (r >> 2) + 4 * half;
                    #pragma unroll
                    for (int c = 0; c < 2; ++c) Sb[c][r] = (tk > l31) ? -3.0e38f : Sb[c][r];
                }
                float mx[2] = { Sa[0][0], Sa[1][0] };
                #pragma unroll
                for (int r = 1; r < 16; ++r) {
                    #pragma unroll
                    for (int c = 0; c < 2; ++c) mx[c] = fmaxf(mx[c], Sa[c][r]);
                }
                #pragma unroll
                for (int r = 0; r < 16; ++r) {
                    #pragma unroll
                    for (int c = 0; c < 2; ++c) mx[c] = fmaxf(mx[c], Sb[c][r]);
                }
                #pragma unroll
                for (int c = 0; c < 2; ++c) mx[c] = fmaxf(mx[c], __shfl_xor(mx[c], 32));
                float sum[2] = { 0.f, 0.f };
                #pragma unroll
                for (int r = 0; r < 16; ++r) {
                    #pragma unroll
                    for (int c = 0; c < 2; ++c) {
                        const float p = EXP2F(Sa[c][r] - mx[c]); Sa[c][r] = p; sum[c] += p;
                    }
                }
                #pragma unroll
                for (int r = 0; r < 16; ++r) {
                    #pragma unroll
                    for (int c = 0; c < 2; ++c) {
                        const float p = EXP2F(Sb[c][r] - mx[c]); Sb[c][r] = p; sum[c] += p;
                    }
                }
                #pragma unroll
                for (int c = 0; c < 2; ++c) sum[c] += __shfl_xor(sum[c], 32);

                unsigned ua[2][8], ub[2][8];
                #pragma unroll
                for (int i = 0; i < 8; ++i) {
                    #pragma unroll
                    for (int c = 0; c < 2; ++c) {
                        union { __bf16 h[2]; unsigned w; } cv;
                        cv.h[0] = (__bf16)Sa[c][2 * i]; cv.h[1] = (__bf16)Sa[c][2 * i + 1];
                        ua[c][i] = cv.w;
                        union { __bf16 h[2]; unsigned w; } cw;
                        cw.h[0] = (__bf16)Sb[c][2 * i]; cw.h[1] = (__bf16)Sb[c][2 * i + 1];
                        ub[c][i] = cw.w;
                    }
                }
                f32x16 O[2] = { zc16, zc16 };
                #pragma unroll
                for (int ch = 0; ch < 4; ++ch) {
                    const int c2 = ch & 1;
                    #pragma unroll
                    for (int c = 0; c < 2; ++c) {
                        const unsigned* uu = (ch < 2) ? ua[c] : ub[c];
                        const unsigned x0 = __shfl_xor(uu[4 * c2 + 0], 32);
                        const unsigned x1 = __shfl_xor(uu[4 * c2 + 1], 32);
                        const unsigned x2 = __shfl_xor(uu[4 * c2 + 2], 32);
                        const unsigned x3 = __shfl_xor(uu[4 * c2 + 3], 32);
                        union { unsigned w[4]; bf16x8 v; } bw;
                        bw.w[0] = half ? x2 : uu[4 * c2 + 0];
                        bw.w[1] = half ? x3 : uu[4 * c2 + 1];
                        bw.w[2] = half ? uu[4 * c2 + 2] : x0;
                        bw.w[3] = half ? uu[4 * c2 + 3] : x1;
                        const bf16x8 vA = (ch == 0) ? vA0[c] : (ch == 1) ? vA1[c]
                                        : (ch == 2) ? vA2[c] : vA3[c];
                        O[c] = __builtin_amdgcn_mfma_f32_32x32x16_bf16(vA, bw.v, O[c], 0, 0, 0);
                    }
                }
                #pragma unroll
                for (int c = 0; c < 2; ++c) {
                    const float inv = RCPF(sum[c]);
                    bf16x4 ov;
                    #pragma unroll
                    for (int r = 0; r < 4; ++r) ov[r] = (__bf16)(O[c][r] * inv);
                    *reinterpret_cast<bf16x4*>(ldsp(qsb[c], 32 + l31, hc + 4 * half)) = ov;
                }
            }
        }
    }
    __syncthreads();

    // ---------------- Phase 4: MLP, dual-column, shared weight frags ----------------
    {
        bf16x8 h0[2], h1[2];
        #pragma unroll
        for (int c = 0; c < 2; ++c) {
            h0[c] = *reinterpret_cast<const bf16x8*>(ldsp(qsb[c], m0 + cl, kb));
            h1[c] = *reinterpret_cast<const bf16x8*>(ldsp(qsb[c], m0 + cl, 32 + kb));
        }
        // 4a: hidden = gelu(attn_out @ W15^T + b15) -> ks (swapped: D[feat][t], b64 stores)
        #pragma unroll
        for (int nt = 0; nt < 4; ++nt) {
            const int nf = nt * 16;
            const bf16x8 w0 = *reinterpret_cast<const bf16x8*>(&W15b[(nf + cl) * Dn + kb]);
            const bf16x8 w1 = *reinterpret_cast<const bf16x8*>(&W15b[(nf + cl) * Dn + 32 + kb]);
            const float4 bs = *reinterpret_cast<const float4*>(&b15[nf + 4 * quad]);
            #pragma unroll
            for (int c = 0; c < 2; ++c) {
                f32x4 acc = {0.f, 0.f, 0.f, 0.f};
                acc = __builtin_amdgcn_mfma_f32_16x16x32_bf16(w0, h0[c], acc, 0, 0, 0);
                acc = __builtin_amdgcn_mfma_f32_16x16x32_bf16(w1, h1[c], acc, 0, 0, 0);
                bf16x4 pk;
                pk[0] = (__bf16)geluf(acc[0] + bs.x);
                pk[1] = (__bf16)geluf(acc[1] + bs.y);
                pk[2] = (__bf16)geluf(acc[2] + bs.z);
                pk[3] = (__bf16)geluf(acc[3] + bs.w);
                *reinterpret_cast<bf16x4*>(ldsp(ksb[c], m0 + cl, nf + 4 * quad)) = pk;
            }
        }
        // No barrier: 4b reads only this wave's 16 rows of ks (same-wave DS in-order).
        bf16x8 g0[2], g1[2];
        #pragma unroll
        for (int c = 0; c < 2; ++c) {
            g0[c] = *reinterpret_cast<const bf16x8*>(ldsp(ksb[c], m0 + cl, kb));
            g1[c] = *reinterpret_cast<const bf16x8*>(ldsp(ksb[c], m0 + cl, 32 + kb));
        }
        const size_t ob = (((size_t)(b * Tn + m0 + cl)) * Nn + n0) * (size_t)Dn;
        #pragma unroll
        for (int nt = 0; nt < 4; ++nt) {
            const int nf = nt * 16;
            const bf16x8 w0 = *reinterpret_cast<const bf16x8*>(&W16b[(nf + cl) * Dn + kb]);
            const bf16x8 w1 = *reinterpret_cast<const bf16x8*>(&W16b[(nf + cl) * Dn + 32 + kb]);
            const float4 bs = *reinterpret_cast<const float4*>(&b16[nf + 4 * quad]);
            #pragma unroll
            for (int c = 0; c < 2; ++c) {
                f32x4 acc = {0.f, 0.f, 0.f, 0.f};
                acc = __builtin_amdgcn_mfma_f32_16x16x32_bf16(w0, g0[c], acc, 0, 0, 0);
                acc = __builtin_amdgcn_mfma_f32_16x16x32_bf16(w1, g1[c], acc, 0, 0, 0);
                float4 ov;
                ov.x = acc[0] + bs.x;
                ov.y = acc[1] + bs.y;
                ov.z = acc[2] + bs.z;
                ov.w = acc[3] + bs.w;
                *reinterpret_cast<float4*>(&Out[ob + (size_t)c * Dn + nf + 4 * quad]) = ov;
            }
        }
    }
}

extern "C" void kernel_launch(void* const* d_in, const int* in_sizes, int n_in,
                              void* d_out, int out_size, void* d_ws, size_t ws_size,
                              hipStream_t stream)
{
    (void)in_sizes; (void)n_in; (void)out_size; (void)ws_size;
    const float* X   = (const float*)d_in[0];
    const float* STE = (const float*)d_in[1];
    const float* W12 = (const float*)d_in[2];
    const float* b12 = (const float*)d_in[3];
    const float* W13 = (const float*)d_in[4];
    const float* b13 = (const float*)d_in[5];
    const float* W14 = (const float*)d_in[6];
    const float* b14 = (const float*)d_in[7];
    const float* W15 = (const float*)d_in[8];
    const float* b15 = (const float*)d_in[9];
    const float* W16 = (const float*)d_in[10];
    const float* b16 = (const float*)d_in[11];
    float* Out = (float*)d_out;
    __bf16* ws = (__bf16*)d_ws;   // needs 65,536 B

    hipLaunchKernelGGL(convert_weights, dim3(128), dim3(256), 0, stream,
                       W12, W13, W14, W15, W16, ws);
    hipLaunchKernelGGL(tam_fused, dim3(Bn * Nn / 2), dim3(256), 0, stream,
                       X, STE, b12, b13, b14, b15, b16, ws, Out);
}

// Round 11
// 243.926 us; speedup vs baseline: 1.1566x; 1.0071x over previous
//
#include <hip/hip_runtime.h>
#include <hip/hip_bf16.h>

// Problem constants (fixed by reference)
#define Bn 16
#define Tn 64
#define Nn 256
#define Kn 8
#define dn 8
#define Dn 64
#define TDn 128   // 2*D

typedef __bf16 bf16x8 __attribute__((ext_vector_type(8)));
typedef __bf16 bf16x4 __attribute__((ext_vector_type(4)));
typedef float  f32x4  __attribute__((ext_vector_type(4)));
typedef float  f32x16 __attribute__((ext_vector_type(16)));

#if __has_builtin(__builtin_amdgcn_exp2f)
#define EXP2F(x) __builtin_amdgcn_exp2f(x)
#else
#define EXP2F(x) exp2f(x)
#endif

#if __has_builtin(__builtin_amdgcn_rcpf)
#define RCPF(x) __builtin_amdgcn_rcpf(x)
#else
#define RCPF(x) (1.0f / (x))
#endif

// tanh-form GELU via native exp2 + rcp (~10 VALU ops vs ~60 for libm erff).
__device__ __forceinline__ float geluf(float x) {
    const float x2 = x * x;
    const float v = x * fmaf(0.10294342f, x2, 2.30220920f);   // 2*log2e*0.79788456*(x+0.044715x^3)
    const float w = EXP2F(-fabsf(v));
    const float r = RCPF(1.0f + w);
    const float t = (1.0f - w) * r;                            // tanh(|u|)
    return fmaf(0.5f * fabsf(x), t, 0.5f * x);
}

__device__ __forceinline__ bf16x8 bzero8() {
    bf16x8 z;
    #pragma unroll
    for (int e = 0; e < 8; ++e) z[e] = (__bf16)0.0f;
    return z;
}

__device__ __forceinline__ bf16x8 pack8(float4 f0, float4 f1) {
    bf16x8 a;
    a[0] = (__bf16)f0.x; a[1] = (__bf16)f0.y;
    a[2] = (__bf16)f0.z; a[3] = (__bf16)f0.w;
    a[4] = (__bf16)f1.x; a[5] = (__bf16)f1.y;
    a[6] = (__bf16)f1.z; a[7] = (__bf16)f1.w;
    return a;
}

// Swizzled LDS addressing: logical [64][64] bf16 tile stored at stride 128 B with
// byte ^= (row&7)<<4. Rows exactly 128 B (no pad); XOR is a multiple of 16 so b64/b128
// alignment is preserved; fixed-column reads across rows spread over 8 16-B slots.
__device__ __forceinline__ char* ldsp(char* base, int row, int col) {
    return base + (((row << 7) + (col << 1)) ^ ((row & 7) << 4));
}

// ---- Kernel 1: convert all weights fp32 -> bf16 into d_ws ----
// ws layout (bf16): [0,24576) Wqkv rows 0-63=W12,64-127=W13,128-191=W14 (row=128 k)
//                   [24576,28672) W15 [64][64]; [28672,32768) W16 [64][64]
__global__ void convert_weights(const float* __restrict__ W12, const float* __restrict__ W13,
                                const float* __restrict__ W14, const float* __restrict__ W15,
                                const float* __restrict__ W16, __bf16* __restrict__ ws)
{
    const int i = blockIdx.x * 256 + threadIdx.x;   // 0..32767
    float v;
    if      (i < 8192)  v = W12[i];
    else if (i < 16384) v = W13[i - 8192];
    else if (i < 24576) v = W14[i - 16384];
    else if (i < 28672) v = W15[i - 24576];
    else                v = W16[i - 28672];
    ws[i] = (__bf16)v;
}

// ---- Kernel 2: fused block per (b, n-pair); 256 threads = 4 waves ----
// R10 (resubmit; R10 bench was an infra failure, never ran): phase 2 re-partitioned
// BY FEATURE BLOCK: wave wv computes q/k/v features [16wv,16wv+16) for ALL 64 t (both
// n-cols) — exactly the features its phase-3 heads {2wv,2wv+1} consume. Everything
// phase 3 reads is same-wave-written -> the phase-2->3 __syncthreads is DELETED
// (waves run decoupled through the bulk of the kernel).
// Bonus: weight frags drop 48->12/thread (hoisted, shared over t-tiles+cols) and each
// t-tile has 6 independent 4-deep MFMA chains (q/k/v x 2 cols) vs 2 before.
// Cost: H re-read per wave (4x volume, same access shape) - intra-block L2 hits.
// LDS 49,152 B -> 3 blocks/CU. Per-col regions (c*24576): vt | qs (+8192) | ks (+16384),
// each swizzled [64][64]. Phase 3: 32x32x16 MFMA, P in registers (lane^32 swap repack).
// Phase 4 (after the one remaining barrier): swapped-operand MLP, dual-column.
__global__ __launch_bounds__(256, 3)
void tam_fused(const float* __restrict__ X,
               const float* __restrict__ STE,
               const float* __restrict__ b12, const float* __restrict__ b13,
               const float* __restrict__ b14, const float* __restrict__ b15,
               const float* __restrict__ b16,
               const __bf16* __restrict__ Wb,   // converted weights in ws
               float* __restrict__ Out)
{
    __shared__ __align__(16) char smem[49152];
    char* const vtb[2] = { smem,         smem + 24576 };
    char* const qsb[2] = { smem + 8192,  smem + 24576 + 8192 };
    char* const ksb[2] = { smem + 16384, smem + 24576 + 16384 };

    const int bn   = blockIdx.x;   // 0..2047
    const int b    = bn >> 7;      // / 128 pairs
    const int n0   = (bn & 127) * 2;
    const int tid  = threadIdx.x;
    const int lane = tid & 63;
    const int wv   = __builtin_amdgcn_readfirstlane(tid >> 6);
    const int cl   = lane & 15;          // 16x16 MFMA col-in-tile / A-row-in-tile
    const int quad = lane >> 4;
    const int kb   = quad * 8;           // 16x16 MFMA k-offset
    const int m0   = wv * 16;            // this wave's row-tile (phase 4)
    const int fb   = wv * 16;            // this wave's FEATURE block (phase 2/3)

    const __bf16* Wqkv = Wb;             // [192][128]
    const __bf16* W15b = Wb + 24576;     // [64][64]
    const __bf16* W16b = Wb + 28672;     // [64][64]

    // ---------------- Phase 2: qkv = gelu(H @ Wqkv^T + b), feature-partitioned ----------------
    // Wave wv owns q feats fb..fb+15 (Wqkv rows fb+), k feats (rows 64+fb+), v feats
    // (rows 128+fb+), for all 64 t, both cols. q/k swapped (D[feat][t]); v unswapped
    // (D[t][feat]) into transposed vt. q pre-scaled by 1/sqrt(8)*log2(e).
    {
        bf16x8 wqA[4], wkA[4], wvB[4];
        #pragma unroll
        for (int kk = 0; kk < 4; ++kk) {
            wqA[kk] = *reinterpret_cast<const bf16x8*>(&Wqkv[(fb + cl) * TDn + kk * 32 + kb]);
            wkA[kk] = *reinterpret_cast<const bf16x8*>(&Wqkv[(64 + fb + cl) * TDn + kk * 32 + kb]);
            wvB[kk] = *reinterpret_cast<const bf16x8*>(&Wqkv[(128 + fb + cl) * TDn + kk * 32 + kb]);
        }
        const float4 bq = *reinterpret_cast<const float4*>(&b12[fb + 4 * quad]);
        const float4 bk = *reinterpret_cast<const float4*>(&b13[fb + 4 * quad]);
        const float  vb = b14[fb + cl];

        #pragma unroll
        for (int tt = 0; tt < 4; ++tt) {
            // H frags for t-tile tt: lane cl = t-in-tile, k = kk*32 + quad*8 (+e).
            // Same bytes serve as swapped-B (col=cl=t) for q/k and unswapped-A (row=cl=t) for v.
            bf16x8 hf[2][4];
            {
                const size_t rb = (((size_t)b * Tn + 16 * tt + cl) * Nn + n0) * (size_t)Dn;
                #pragma unroll
                for (int c = 0; c < 2; ++c) {
                    const float4* Xr = reinterpret_cast<const float4*>(X + rb + c * Dn);
                    const float4* Sr = reinterpret_cast<const float4*>(STE + rb + c * Dn);
                    const int fi = quad * 2;
                    hf[c][0] = pack8(Xr[fi],     Xr[fi + 1]);
                    hf[c][1] = pack8(Xr[8 + fi], Xr[8 + fi + 1]);
                    hf[c][2] = pack8(Sr[fi],     Sr[fi + 1]);
                    hf[c][3] = pack8(Sr[8 + fi], Sr[8 + fi + 1]);
                }
            }
            // 6 independent 4-deep MFMA chains: q/k/v x 2 cols.
            f32x4 qa[2] = { {0.f,0.f,0.f,0.f}, {0.f,0.f,0.f,0.f} };
            f32x4 ka[2] = { {0.f,0.f,0.f,0.f}, {0.f,0.f,0.f,0.f} };
            f32x4 va[2] = { {0.f,0.f,0.f,0.f}, {0.f,0.f,0.f,0.f} };
            #pragma unroll
            for (int kk = 0; kk < 4; ++kk) {
                #pragma unroll
                for (int c = 0; c < 2; ++c) {
                    qa[c] = __builtin_amdgcn_mfma_f32_16x16x32_bf16(wqA[kk], hf[c][kk], qa[c], 0, 0, 0);
                    ka[c] = __builtin_amdgcn_mfma_f32_16x16x32_bf16(wkA[kk], hf[c][kk], ka[c], 0, 0, 0);
                    va[c] = __builtin_amdgcn_mfma_f32_16x16x32_bf16(hf[c][kk], wvB[kk], va[c], 0, 0, 0);
                }
            }
            #pragma unroll
            for (int c = 0; c < 2; ++c) {
                // q/k swapped C: col = cl = t-in-tile, row = 4q+r = feat-in-block.
                bf16x4 pq;
                pq[0] = (__bf16)(geluf(qa[c][0] + bq.x) * 0.51006951f);
                pq[1] = (__bf16)(geluf(qa[c][1] + bq.y) * 0.51006951f);
                pq[2] = (__bf16)(geluf(qa[c][2] + bq.z) * 0.51006951f);
                pq[3] = (__bf16)(geluf(qa[c][3] + bq.w) * 0.51006951f);
                *reinterpret_cast<bf16x4*>(ldsp(qsb[c], 16 * tt + cl, fb + 4 * quad)) = pq;
                bf16x4 pk;
                pk[0] = (__bf16)geluf(ka[c][0] + bk.x);
                pk[1] = (__bf16)geluf(ka[c][1] + bk.y);
                pk[2] = (__bf16)geluf(ka[c][2] + bk.z);
                pk[3] = (__bf16)geluf(ka[c][3] + bk.w);
                *reinterpret_cast<bf16x4*>(ldsp(ksb[c], 16 * tt + cl, fb + 4 * quad)) = pk;
                // v unswapped C: col = cl = feat-in-block, row = 4q+r = t-in-tile.
                bf16x4 pv;
                pv[0] = (__bf16)geluf(va[c][0] + vb);
                pv[1] = (__bf16)geluf(va[c][1] + vb);
                pv[2] = (__bf16)geluf(va[c][2] + vb);
                pv[3] = (__bf16)geluf(va[c][3] + vb);
                *reinterpret_cast<bf16x4*>(ldsp(vtb[c], fb + cl, 16 * tt + 4 * quad)) = pv;
            }
        }
    }
    // NO barrier: phase 3 reads only columns/rows this wave just wrote (same-wave DS
    // ops are in-order). Waves proceed decoupled through phases 2+3.

    // ---------------- Phase 3: 32x32x16 MFMA attention, dual-column, P in registers -------
    // Wave wv owns heads {2wv, 2wv+1} (columns [16wv,16wv+16) of qs/ks/vt) in BOTH n-cols.
    //   A: row = lane&31, k = (lane>>5)*8 + e;  B: col = lane&31, k = (lane>>5)*8 + e
    //   C: col = lane&31, row = (reg&3) + 8*(reg>>2) + 4*(lane>>5)
    {
        const int half = lane >> 5;
        const int l31  = lane & 31;

        for (int hh = 0; hh < 2; ++hh) {
            const int hc = 8 * (2 * wv + hh);

            bf16x8 kA0[2], kA1[2], qB0[2], qB1[2], vA0[2], vA1[2];
            #pragma unroll
            for (int c = 0; c < 2; ++c) {
                kA0[c] = bzero8(); kA1[c] = bzero8(); qB0[c] = bzero8(); qB1[c] = bzero8();
                vA0[c] = bzero8(); vA1[c] = bzero8();
                if (half == 0) {
                    kA0[c] = *reinterpret_cast<const bf16x8*>(ldsp(ksb[c],  0 + l31, hc));
                    kA1[c] = *reinterpret_cast<const bf16x8*>(ldsp(ksb[c], 32 + l31, hc));
                    qB0[c] = *reinterpret_cast<const bf16x8*>(ldsp(qsb[c],  0 + l31, hc));
                    qB1[c] = *reinterpret_cast<const bf16x8*>(ldsp(qsb[c], 32 + l31, hc));
                }
                if (l31 < 8) {
                    vA0[c] = *reinterpret_cast<const bf16x8*>(ldsp(vtb[c], hc + l31,  0 + 8 * half));
                    vA1[c] = *reinterpret_cast<const bf16x8*>(ldsp(vtb[c], hc + l31, 16 + 8 * half));
                }
            }

            f32x16 zc16;
            #pragma unroll
            for (int r = 0; r < 16; ++r) zc16[r] = 0.f;

            // ================= tq-tile 0 (tq = l31; tk-tile 0 only, causal) =================
            {
                f32x16 S[2];
                #pragma unroll
                for (int c = 0; c < 2; ++c)
                    S[c] = __builtin_amdgcn_mfma_f32_32x32x16_bf16(kA0[c], qB0[c], zc16, 0, 0, 0);
                #pragma unroll
                for (int r = 0; r < 16; ++r) {
                    const int tk = (r & 3) + 8 * (r >> 2) + 4 * half;
                    #pragma unroll
                    for (int c = 0; c < 2; ++c) S[c][r] = (tk > l31) ? -3.0e38f : S[c][r];
                }
                float mx[2] = { S[0][0], S[1][0] };
                #pragma unroll
                for (int r = 1; r < 16; ++r) {
                    #pragma unroll
                    for (int c = 0; c < 2; ++c) mx[c] = fmaxf(mx[c], S[c][r]);
                }
                #pragma unroll
                for (int c = 0; c < 2; ++c) mx[c] = fmaxf(mx[c], __shfl_xor(mx[c], 32));
                float sum[2] = { 0.f, 0.f };
                #pragma unroll
                for (int r = 0; r < 16; ++r) {
                    #pragma unroll
                    for (int c = 0; c < 2; ++c) {
                        const float p = EXP2F(S[c][r] - mx[c]);
                        S[c][r] = p; sum[c] += p;
                    }
                }
                #pragma unroll
                for (int c = 0; c < 2; ++c) sum[c] += __shfl_xor(sum[c], 32);

                unsigned u[2][8];
                #pragma unroll
                for (int i = 0; i < 8; ++i) {
                    #pragma unroll
                    for (int c = 0; c < 2; ++c) {
                        union { __bf16 h[2]; unsigned w; } cv;
                        cv.h[0] = (__bf16)S[c][2 * i]; cv.h[1] = (__bf16)S[c][2 * i + 1];
                        u[c][i] = cv.w;
                    }
                }
                f32x16 O[2] = { zc16, zc16 };
                #pragma unroll
                for (int ch = 0; ch < 2; ++ch) {
                    #pragma unroll
                    for (int c = 0; c < 2; ++c) {
                        const unsigned x0 = __shfl_xor(u[c][4 * ch + 0], 32);
                        const unsigned x1 = __shfl_xor(u[c][4 * ch + 1], 32);
                        const unsigned x2 = __shfl_xor(u[c][4 * ch + 2], 32);
                        const unsigned x3 = __shfl_xor(u[c][4 * ch + 3], 32);
                        union { unsigned w[4]; bf16x8 v; } bw;
                        bw.w[0] = half ? x2 : u[c][4 * ch + 0];
                        bw.w[1] = half ? x3 : u[c][4 * ch + 1];
                        bw.w[2] = half ? u[c][4 * ch + 2] : x0;
                        bw.w[3] = half ? u[c][4 * ch + 3] : x1;
                        O[c] = __builtin_amdgcn_mfma_f32_32x32x16_bf16(ch ? vA1[c] : vA0[c],
                                                                       bw.v, O[c], 0, 0, 0);
                    }
                }
                #pragma unroll
                for (int c = 0; c < 2; ++c) {
                    const float inv = RCPF(sum[c]);
                    bf16x4 ov;
                    #pragma unroll
                    for (int r = 0; r < 4; ++r) ov[r] = (__bf16)(O[c][r] * inv);
                    *reinterpret_cast<bf16x4*>(ldsp(qsb[c], l31, hc + 4 * half)) = ov;
                }
            }

            // ================= tq-tile 1 (tq = 32+l31; tk-tiles 0 and 1) =================
            {
                bf16x8 vA2[2], vA3[2];
                #pragma unroll
                for (int c = 0; c < 2; ++c) {
                    vA2[c] = bzero8(); vA3[c] = bzero8();
                    if (l31 < 8) {
                        vA2[c] = *reinterpret_cast<const bf16x8*>(ldsp(vtb[c], hc + l31, 32 + 8 * half));
                        vA3[c] = *reinterpret_cast<const bf16x8*>(ldsp(vtb[c], hc + l31, 48 + 8 * half));
                    }
                }
                f32x16 Sa[2], Sb[2];
                #pragma unroll
                for (int c = 0; c < 2; ++c) {
                    Sa[c] = __builtin_amdgcn_mfma_f32_32x32x16_bf16(kA0[c], qB1[c], zc16, 0, 0, 0);
                    Sb[c] = __builtin_amdgcn_mfma_f32_32x32x16_bf16(kA1[c], qB1[c], zc16, 0, 0, 0);
                }
                #pragma unroll
                for (int r = 0; r < 16; ++r) {   // mask only the diagonal tile (tk 32..63)
                    const int tk = (r & 3) + 8 * (r >> 2) + 4 * half;
                    #pragma unroll
                    for (int c = 0; c < 2; ++c) Sb[c][r] = (tk > l31) ? -3.0e38f : Sb[c][r];
                }
                float mx[2] = { Sa[0][0], Sa[1][0] };
                #pragma unroll
                for (int r = 1; r < 16; ++r) {
                    #pragma unroll
                    for (int c = 0; c < 2; ++c) mx[c] = fmaxf(mx[c], Sa[c][r]);
                }
                #pragma unroll
                for (int r = 0; r < 16; ++r) {
                    #pragma unroll
                    for (int c = 0; c < 2; ++c) mx[c] = fmaxf(mx[c], Sb[c][r]);
                }
                #pragma unroll
                for (int c = 0; c < 2; ++c) mx[c] = fmaxf(mx[c], __shfl_xor(mx[c], 32));
                float sum[2] = { 0.f, 0.f };
                #pragma unroll
                for (int r = 0; r < 16; ++r) {
                    #pragma unroll
                    for (int c = 0; c < 2; ++c) {
                        const float p = EXP2F(Sa[c][r] - mx[c]); Sa[c][r] = p; sum[c] += p;
                    }
                }
                #pragma unroll
                for (int r = 0; r < 16; ++r) {
                    #pragma unroll
                    for (int c = 0; c < 2; ++c) {
                        const float p = EXP2F(Sb[c][r] - mx[c]); Sb[c][r] = p; sum[c] += p;
                    }
                }
                #pragma unroll
                for (int c = 0; c < 2; ++c) sum[c] += __shfl_xor(sum[c], 32);

                unsigned ua[2][8], ub[2][8];
                #pragma unroll
                for (int i = 0; i < 8; ++i) {
                    #pragma unroll
                    for (int c = 0; c < 2; ++c) {
                        union { __bf16 h[2]; unsigned w; } cv;
                        cv.h[0] = (__bf16)Sa[c][2 * i]; cv.h[1] = (__bf16)Sa[c][2 * i + 1];
                        ua[c][i] = cv.w;
                        union { __bf16 h[2]; unsigned w; } cw;
                        cw.h[0] = (__bf16)Sb[c][2 * i]; cw.h[1] = (__bf16)Sb[c][2 * i + 1];
                        ub[c][i] = cw.w;
                    }
                }
                f32x16 O[2] = { zc16, zc16 };
                #pragma unroll
                for (int ch = 0; ch < 4; ++ch) {
                    const int c2 = ch & 1;
                    #pragma unroll
                    for (int c = 0; c < 2; ++c) {
                        const unsigned* uu = (ch < 2) ? ua[c] : ub[c];
                        const unsigned x0 = __shfl_xor(uu[4 * c2 + 0], 32);
                        const unsigned x1 = __shfl_xor(uu[4 * c2 + 1], 32);
                        const unsigned x2 = __shfl_xor(uu[4 * c2 + 2], 32);
                        const unsigned x3 = __shfl_xor(uu[4 * c2 + 3], 32);
                        union { unsigned w[4]; bf16x8 v; } bw;
                        bw.w[0] = half ? x2 : uu[4 * c2 + 0];
                        bw.w[1] = half ? x3 : uu[4 * c2 + 1];
                        bw.w[2] = half ? uu[4 * c2 + 2] : x0;
                        bw.w[3] = half ? uu[4 * c2 + 3] : x1;
                        const bf16x8 vA = (ch == 0) ? vA0[c] : (ch == 1) ? vA1[c]
                                        : (ch == 2) ? vA2[c] : vA3[c];
                        O[c] = __builtin_amdgcn_mfma_f32_32x32x16_bf16(vA, bw.v, O[c], 0, 0, 0);
                    }
                }
                #pragma unroll
                for (int c = 0; c < 2; ++c) {
                    const float inv = RCPF(sum[c]);
                    bf16x4 ov;
                    #pragma unroll
                    for (int r = 0; r < 4; ++r) ov[r] = (__bf16)(O[c][r] * inv);
                    *reinterpret_cast<bf16x4*>(ldsp(qsb[c], 32 + l31, hc + 4 * half)) = ov;
                }
            }
        }
    }
    __syncthreads();   // phase 4 reads attention output across all heads (cross-wave)

    // ---------------- Phase 4: MLP, dual-column, shared weight frags ----------------
    {
        bf16x8 h0[2], h1[2];
        #pragma unroll
        for (int c = 0; c < 2; ++c) {
            h0[c] = *reinterpret_cast<const bf16x8*>(ldsp(qsb[c], m0 + cl, kb));
            h1[c] = *reinterpret_cast<const bf16x8*>(ldsp(qsb[c], m0 + cl, 32 + kb));
        }
        // 4a: hidden = gelu(attn_out @ W15^T + b15) -> ks (swapped: D[feat][t], b64 stores)
        #pragma unroll
        for (int nt = 0; nt < 4; ++nt) {
            const int nf = nt * 16;
            const bf16x8 w0 = *reinterpret_cast<const bf16x8*>(&W15b[(nf + cl) * Dn + kb]);
            const bf16x8 w1 = *reinterpret_cast<const bf16x8*>(&W15b[(nf + cl) * Dn + 32 + kb]);
            const float4 bs = *reinterpret_cast<const float4*>(&b15[nf + 4 * quad]);
            #pragma unroll
            for (int c = 0; c < 2; ++c) {
                f32x4 acc = {0.f, 0.f, 0.f, 0.f};
                acc = __builtin_amdgcn_mfma_f32_16x16x32_bf16(w0, h0[c], acc, 0, 0, 0);
                acc = __builtin_amdgcn_mfma_f32_16x16x32_bf16(w1, h1[c], acc, 0, 0, 0);
                bf16x4 pk;
                pk[0] = (__bf16)geluf(acc[0] + bs.x);
                pk[1] = (__bf16)geluf(acc[1] + bs.y);
                pk[2] = (__bf16)geluf(acc[2] + bs.z);
                pk[3] = (__bf16)geluf(acc[3] + bs.w);
                *reinterpret_cast<bf16x4*>(ldsp(ksb[c], m0 + cl, nf + 4 * quad)) = pk;
            }
        }
        // No barrier: 4b reads only this wave's 16 rows of ks (same-wave DS in-order).
        bf16x8 g0[2], g1[2];
        #pragma unroll
        for (int c = 0; c < 2; ++c) {
            g0[c] = *reinterpret_cast<const bf16x8*>(ldsp(ksb[c], m0 + cl, kb));
            g1[c] = *reinterpret_cast<const bf16x8*>(ldsp(ksb[c], m0 + cl, 32 + kb));
        }
        const size_t ob = (((size_t)(b * Tn + m0 + cl)) * Nn + n0) * (size_t)Dn;
        #pragma unroll
        for (int nt = 0; nt < 4; ++nt) {
            const int nf = nt * 16;
            const bf16x8 w0 = *reinterpret_cast<const bf16x8*>(&W16b[(nf + cl) * Dn + kb]);
            const bf16x8 w1 = *reinterpret_cast<const bf16x8*>(&W16b[(nf + cl) * Dn + 32 + kb]);
            const float4 bs = *reinterpret_cast<const float4*>(&b16[nf + 4 * quad]);
            #pragma unroll
            for (int c = 0; c < 2; ++c) {
                f32x4 acc = {0.f, 0.f, 0.f, 0.f};
                acc = __builtin_amdgcn_mfma_f32_16x16x32_bf16(w0, g0[c], acc, 0, 0, 0);
                acc = __builtin_amdgcn_mfma_f32_16x16x32_bf16(w1, g1[c], acc, 0, 0, 0);
                float4 ov;
                ov.x = acc[0] + bs.x;
                ov.y = acc[1] + bs.y;
                ov.z = acc[2] + bs.z;
                ov.w = acc[3] + bs.w;
                *reinterpret_cast<float4*>(&Out[ob + (size_t)c * Dn + nf + 4 * quad]) = ov;
            }
        }
    }
}

extern "C" void kernel_launch(void* const* d_in, const int* in_sizes, int n_in,
                              void* d_out, int out_size, void* d_ws, size_t ws_size,
                              hipStream_t stream)
{
    (void)in_sizes; (void)n_in; (void)out_size; (void)ws_size;
    const float* X   = (const float*)d_in[0];
    const float* STE = (const float*)d_in[1];
    const float* W12 = (const float*)d_in[2];
    const float* b12 = (const float*)d_in[3];
    const float* W13 = (const float*)d_in[4];
    const float* b13 = (const float*)d_in[5];
    const float* W14 = (const float*)d_in[6];
    const float* b14 = (const float*)d_in[7];
    const float* W15 = (const float*)d_in[8];
    const float* b15 = (const float*)d_in[9];
    const float* W16 = (const float*)d_in[10];
    const float* b16 = (const float*)d_in[11];
    float* Out = (float*)d_out;
    __bf16* ws = (__bf16*)d_ws;   // needs 65,536 B

    hipLaunchKernelGGL(convert_weights, dim3(128), dim3(256), 0, stream,
                       W12, W13, W14, W15, W16, ws);
    hipLaunchKernelGGL(tam_fused, dim3(Bn * Nn / 2), dim3(256), 0, stream,
                       X, STE, b12, b13, b14, b15, b16, ws, Out);
}